// Round 17
// baseline (168.120 us; speedup 1.0000x reference)
//
#include <hip/hip_runtime.h>
#include <hip/hip_bf16.h>
#include <cstddef>

// ---- problem constants ----
#define Bc   2
#define Lc   8192
#define TGT  6146          // L - RF, RF = 2046
#define NL   20            // layers
#define RCc  32
#define DCc  32
#define SCc  1024
#define ECc  512
#define OCc  256
#define KTOT (NL * DCc)    // 640
#define TTILES 49          // ceil(TGT/128)
#define T64   97           // ceil(TGT/64)

typedef __attribute__((ext_vector_type(4))) float f32x4;
typedef __attribute__((ext_vector_type(8))) short bf16x8;
typedef __attribute__((ext_vector_type(4))) int i32x4;
typedef __attribute__((ext_vector_type(2))) int i32x2;

typedef __attribute__((address_space(1))) void* as1v;
typedef __attribute__((address_space(3))) void* as3v;

__device__ inline bf16x8 cvt8(const float4* p) {
    float4 a = p[0], b = p[1];
    union { bf16x8 v; __hip_bfloat16 h[8]; } u;
    u.h[0] = __float2bfloat16(a.x); u.h[1] = __float2bfloat16(a.y);
    u.h[2] = __float2bfloat16(a.z); u.h[3] = __float2bfloat16(a.w);
    u.h[4] = __float2bfloat16(b.x); u.h[5] = __float2bfloat16(b.y);
    u.h[6] = __float2bfloat16(b.z); u.h[7] = __float2bfloat16(b.w);
    return u.v;
}

// ============================================================
// prep kernel: weight packs (blocks [0,npack)) + input 1x1 conv
// ============================================================
__global__ __launch_bounds__(256) void prep_kernel(
    const float* __restrict__ x,        // [B][256][L]
    const float* __restrict__ iw,       // [32][256]
    float* __restrict__ res_out,        // [B][32][L]
    const float* __restrict__ split_w,
    const float* __restrict__ f1_w,
    const float* __restrict__ f2_w,
    const float* __restrict__ filt,
    const float* __restrict__ gate,
    const float* __restrict__ resw,
    __hip_bfloat16* __restrict__ Wp1,
    __hip_bfloat16* __restrict__ Wp2,
    __hip_bfloat16* __restrict__ Wp3,
    __hip_bfloat16* __restrict__ wfgp,
    __hip_bfloat16* __restrict__ wrp,
    int npack)
{
    __shared__ float ws[32][256];
    __shared__ float xs[64][64];
    int tid = threadIdx.x;

    if ((int)blockIdx.x < npack) {
        int idx = blockIdx.x * 256 + tid;
        const int N1 = SCc * KTOT, N2 = ECc * SCc, N3 = OCc * ECc, N4 = NL * 64 * 64;
        if (idx < N1) {
            int m = idx / KTOT, k = idx % KTOT;
            int i = k >> 5, c = k & 31;
            Wp1[idx] = __float2bfloat16(split_w[((size_t)i * SCc + m) * DCc + c]);
            return;
        }
        idx -= N1;
        if (idx < N2) { Wp2[idx] = __float2bfloat16(f1_w[idx]); return; }
        idx -= N2;
        if (idx < N3) { Wp3[idx] = __float2bfloat16(f2_w[idx]); return; }
        idx -= N3;
        if (idx < N4) {
            int li = idx / 4096, r = idx % 4096;
            int m = r >> 6, k = r & 63;
            int tap = k >> 5, ic = k & 31;
            float v = (m < 32) ? filt[(size_t)li * 2048 + (m * 32 + ic) * 2 + tap]
                               : gate[(size_t)li * 2048 + ((m - 32) * 32 + ic) * 2 + tap];
            int slot = (k >> 3) ^ (m & 7);
            wfgp[((size_t)li * 64 + m) * 64 + slot * 8 + (k & 7)] = __float2bfloat16(v);
            if (r < 2048) {
                int m2 = r >> 6;
                float v2 = (k < 32) ? resw[(size_t)li * 1024 + m2 * 32 + k] : 0.f;
                wrp[((size_t)li * 32 + m2) * 64 + slot * 8 + (k & 7)] = __float2bfloat16(v2);
            }
        }
        return;
    }

    // ---- input conv part ----
    int bid = blockIdx.x - npack;
    int b   = bid >> 7;
    int t0  = (bid & 127) * 64;

    for (int idx = tid; idx < 32 * 256; idx += 256)
        ws[idx >> 8][idx & 255] = iw[idx];

    int tl = tid & 63, qq = tid >> 6, oc0 = qq * 8;
    float acc[8] = {};

    for (int icc = 0; icc < 4; ++icc) {
        __syncthreads();
        for (int idx = tid; idx < 64 * 64; idx += 256) {
            int icl = idx >> 6, tll = idx & 63;
            xs[icl][tll] = x[((size_t)b * 256 + icc * 64 + icl) * Lc + t0 + tll];
        }
        __syncthreads();
        for (int icl = 0; icl < 64; icl += 4) {
            float x0 = xs[icl][tl], x1 = xs[icl + 1][tl];
            float x2 = xs[icl + 2][tl], x3 = xs[icl + 3][tl];
#pragma unroll
            for (int j = 0; j < 8; ++j) {
                const float4 w4 = *(const float4*)&ws[oc0 + j][icc * 64 + icl];
                acc[j] += w4.x * x0 + w4.y * x1 + w4.z * x2 + w4.w * x3;
            }
        }
    }
#pragma unroll
    for (int j = 0; j < 8; ++j)
        res_out[((size_t)b * 32 + oc0 + j) * Lc + t0 + tl] = acc[j];
}

// ============================================================
// grouped layers d=1..16, 32-out tiles, 256 thr, 2 blocks/CU.
// Math bit-identical to the 64-tile version (same taps/order).
// ============================================================
__global__ __launch_bounds__(256) void layer_group5(
    const float* __restrict__ res_in,
    float* __restrict__ res_out,
    __hip_bfloat16* __restrict__ outsT,
    const __hip_bfloat16* __restrict__ wfgp,
    const __hip_bfloat16* __restrict__ wrp,
    const float* __restrict__ cond,
    const float* __restrict__ gcf_w,
    const float* __restrict__ gcs_w,
    int l0)
{
    constexpr int W = 64, H = 32, NT = 4;
    __shared__ __align__(16) float resL[W * 36];
    __shared__ __align__(16) unsigned short OsL[W * 40];
    __shared__ __align__(16) i32x4 Wf[2][64 * 8];
    __shared__ __align__(16) i32x4 Wrs[2][32 * 8];

    int tid  = threadIdx.x;
    int b    = blockIdx.y;
    int t0   = blockIdx.x * 32;
    int lane = tid & 63, wid = tid >> 6;   // wid 0..3
    int r15  = lane & 15, q = lane >> 4;

    const float* rb = res_in + (size_t)b * 32 * Lc;
    for (int idx = tid; idx < W * 32; idx += 256) {
        int ch = idx >> 6, tl = idx & 63;
        int tg = t0 - H + tl;
        resL[tl * 36 + ch] = (tg >= 0) ? rb[(size_t)ch * Lc + tg] : 0.f;
    }

    auto issueW = [&](int bufi, int li2) {
        const __hip_bfloat16* wfg = wfgp + (size_t)li2 * 4096;
        const __hip_bfloat16* wrl = wrp  + (size_t)li2 * 2048;
        __builtin_amdgcn_global_load_lds(
            (as1v)(void*)((const i32x4*)wfg + wid * 64 + lane),
            (as3v)(void*)&Wf[bufi][wid * 64], 16, 0, 0);
        __builtin_amdgcn_global_load_lds(
            (as1v)(void*)((const i32x4*)wfg + (wid + 4) * 64 + lane),
            (as3v)(void*)&Wf[bufi][(wid + 4) * 64], 16, 0, 0);
        __builtin_amdgcn_global_load_lds(
            (as1v)(void*)((const i32x4*)wrl + wid * 64 + lane),
            (as3v)(void*)&Wrs[bufi][wid * 64], 16, 0, 0);
    };
    issueW(0, l0);

#pragma unroll
    for (int i = 0; i < 5; ++i) {
        const int cur = i & 1;
        int li = l0 + i;
        int d  = 1 << i;

        float gf = 0.f, gg = 0.f;
#pragma unroll
        for (int c = 0; c < 5; ++c) {
            gf += gcf_w[li * 5 + c] * cond[b * 5 + c];
            gg += gcs_w[li * 5 + c] * cond[b * 5 + c];
        }
        __syncthreads();
        if (i + 1 < 5) issueW(cur ^ 1, li + 1);

        const bf16x8* Wv = (const bf16x8*)Wf[cur];
        {
            int tt = wid;                       // NT==4 waves cover all tiles
            int ct0 = tt * 16;
            int srow0 = ct0 + r15 - d; if (srow0 < 0) srow0 = 0;
            int srow1 = ct0 + r15;
            bf16x8 a0 = cvt8((const float4*)&resL[srow0 * 36 + q * 8]);
            bf16x8 a1 = cvt8((const float4*)&resL[srow1 * 36 + q * 8]);
            int sg0 = q ^ (r15 & 7), sg1 = (4 + q) ^ (r15 & 7);
            f32x4 acc[4] = {};
#pragma unroll
            for (int fj = 0; fj < 4; ++fj)
                acc[fj] = __builtin_amdgcn_mfma_f32_16x16x32_bf16(
                    a0, Wv[(fj * 16 + r15) * 8 + sg0], acc[fj], 0, 0, 0);
#pragma unroll
            for (int fj = 0; fj < 4; ++fj)
                acc[fj] = __builtin_amdgcn_mfma_f32_16x16x32_bf16(
                    a1, Wv[(fj * 16 + r15) * 8 + sg1], acc[fj], 0, 0, 0);
#pragma unroll
            for (int fj = 0; fj < 2; ++fj) {
#pragma unroll
                for (int r = 0; r < 4; ++r) {
                    float F = acc[fj][r] + gf;
                    float G = acc[fj + 2][r] + gg;
                    float th  = 1.f - 2.f / (__expf(2.f * F) + 1.f);
                    float sgm = 1.f / (1.f + __expf(-G));
                    float o   = th * sgm;
                    int col = ct0 + q * 4 + r;
                    int ch  = fj * 16 + r15;
                    __hip_bfloat16 ob = __float2bfloat16(o);
                    OsL[col * 40 + ch] = *(unsigned short*)&ob;
                }
            }
        }
        __syncthreads();

        {
            int row = tid >> 3, chunk = tid & 7;   // 32 rows x 8 chunks
            int tg = t0 + row;
            if (tg >= Lc - TGT) {
                i32x2 v = *(const i32x2*)&OsL[(H + row) * 40 + chunk * 4];
                *(i32x2*)(outsT + ((size_t)(b * TGT + tg - (Lc - TGT))) * KTOT
                          + li * 32 + chunk * 4) = v;
            }
        }

        const bf16x8* Rv = (const bf16x8*)Wrs[cur];
        const bf16x8* Ov = (const bf16x8*)OsL;
        {
            int tt = wid;
            int ct0 = tt * 16;
            bf16x8 ao = Ov[(ct0 + r15) * 5 + q];
            int sg = q ^ (r15 & 7);
            f32x4 racc[2] = {};
#pragma unroll
            for (int fj = 0; fj < 2; ++fj)
                racc[fj] = __builtin_amdgcn_mfma_f32_16x16x32_bf16(
                    ao, Rv[(fj * 16 + r15) * 8 + sg], racc[fj], 0, 0, 0);
#pragma unroll
            for (int fj = 0; fj < 2; ++fj)
#pragma unroll
                for (int r = 0; r < 4; ++r) {
                    int col = ct0 + q * 4 + r;
                    int ch  = fj * 16 + r15;
                    if (t0 + col - H >= 0)
                        resL[col * 36 + ch] += racc[fj][r];
                }
        }
    }
    __syncthreads();

    {
        int ch = tid >> 3, t4 = (tid & 7) * 4;   // 32 ch x 32 t
        float v[4];
#pragma unroll
        for (int j = 0; j < 4; ++j) v[j] = resL[(H + t4 + j) * 36 + ch];
        float* ro = res_out + ((size_t)(b * 32) + ch) * Lc + t0 + t4;
        *(float4*)ro = make_float4(v[0], v[1], v[2], v[3]);
    }
}

// ============================================================
// strided grouped layers d=32..512 (stride-32 residues),
// 32-out tiles, 256 thr, 2 blocks/CU. Bit-identical math.
// ============================================================
template <bool LASTHALF>
__global__ __launch_bounds__(256) void layer_groupS(
    const float* __restrict__ res_in,
    float* __restrict__ res_out,
    __hip_bfloat16* __restrict__ outsT,
    const __hip_bfloat16* __restrict__ wfgp,
    const __hip_bfloat16* __restrict__ wrp,
    const float* __restrict__ cond,
    const float* __restrict__ gcf_w,
    const float* __restrict__ gcs_w,
    int l0)
{
    constexpr int W = 64, H = 32, NT = 4, S = 32;
    __shared__ __align__(16) float resL[W * 36];
    __shared__ __align__(16) unsigned short OsL[W * 40];
    __shared__ __align__(16) i32x4 Wf[2][64 * 8];
    __shared__ __align__(16) i32x4 Wrs[2][32 * 8];

    int tid  = threadIdx.x;
    int b    = blockIdx.y;
    int r    = blockIdx.x & 31;          // residue mod 32
    int c0   = (blockIdx.x >> 5) * 32;   // compressed col base (0..224)
    int lane = tid & 63, wid = tid >> 6;
    int r15  = lane & 15, q = lane >> 4;

    const float* rb = res_in + (size_t)b * 32 * Lc;
    for (int idx = tid; idx < W * 32; idx += 256) {
        int ch = idx >> 6, col = idx & 63;
        int cj = c0 + col - H;
        resL[col * 36 + ch] = (cj >= 0) ? rb[(size_t)ch * Lc + r + S * cj] : 0.f;
    }

    auto issueW = [&](int bufi, int li2) {
        const __hip_bfloat16* wfg = wfgp + (size_t)li2 * 4096;
        const __hip_bfloat16* wrl = wrp  + (size_t)li2 * 2048;
        __builtin_amdgcn_global_load_lds(
            (as1v)(void*)((const i32x4*)wfg + wid * 64 + lane),
            (as3v)(void*)&Wf[bufi][wid * 64], 16, 0, 0);
        __builtin_amdgcn_global_load_lds(
            (as1v)(void*)((const i32x4*)wfg + (wid + 4) * 64 + lane),
            (as3v)(void*)&Wf[bufi][(wid + 4) * 64], 16, 0, 0);
        __builtin_amdgcn_global_load_lds(
            (as1v)(void*)((const i32x4*)wrl + wid * 64 + lane),
            (as3v)(void*)&Wrs[bufi][wid * 64], 16, 0, 0);
    };
    issueW(0, l0);

#pragma unroll
    for (int i = 0; i < 5; ++i) {
        const int cur = i & 1;
        int li = l0 + i;
        int dc = 1 << i;

        float gf = 0.f, gg = 0.f;
#pragma unroll
        for (int c = 0; c < 5; ++c) {
            gf += gcf_w[li * 5 + c] * cond[b * 5 + c];
            gg += gcs_w[li * 5 + c] * cond[b * 5 + c];
        }
        __syncthreads();
        if (i + 1 < 5) issueW(cur ^ 1, li + 1);

        const bf16x8* Wv = (const bf16x8*)Wf[cur];
        {
            int tt = wid;
            int ct0 = tt * 16;
            int srow0 = ct0 + r15 - dc; if (srow0 < 0) srow0 = 0;
            int srow1 = ct0 + r15;
            bf16x8 a0 = cvt8((const float4*)&resL[srow0 * 36 + q * 8]);
            bf16x8 a1 = cvt8((const float4*)&resL[srow1 * 36 + q * 8]);
            int sg0 = q ^ (r15 & 7), sg1 = (4 + q) ^ (r15 & 7);
            f32x4 acc[4] = {};
#pragma unroll
            for (int fj = 0; fj < 4; ++fj)
                acc[fj] = __builtin_amdgcn_mfma_f32_16x16x32_bf16(
                    a0, Wv[(fj * 16 + r15) * 8 + sg0], acc[fj], 0, 0, 0);
#pragma unroll
            for (int fj = 0; fj < 4; ++fj)
                acc[fj] = __builtin_amdgcn_mfma_f32_16x16x32_bf16(
                    a1, Wv[(fj * 16 + r15) * 8 + sg1], acc[fj], 0, 0, 0);
#pragma unroll
            for (int fj = 0; fj < 2; ++fj) {
#pragma unroll
                for (int rr = 0; rr < 4; ++rr) {
                    float F = acc[fj][rr] + gf;
                    float G = acc[fj + 2][rr] + gg;
                    float th  = 1.f - 2.f / (__expf(2.f * F) + 1.f);
                    float sgm = 1.f / (1.f + __expf(-G));
                    float o   = th * sgm;
                    int col = ct0 + q * 4 + rr;
                    int ch  = fj * 16 + r15;
                    __hip_bfloat16 ob = __float2bfloat16(o);
                    OsL[col * 40 + ch] = *(unsigned short*)&ob;
                }
            }
        }
        __syncthreads();

        {
            int row = tid >> 3, chunk = tid & 7;   // 32 rows
            int t = r + S * (c0 + row);
            if (t >= Lc - TGT) {
                i32x2 v = *(const i32x2*)&OsL[(H + row) * 40 + chunk * 4];
                *(i32x2*)(outsT + ((size_t)(b * TGT + t - (Lc - TGT))) * KTOT
                          + li * 32 + chunk * 4) = v;
            }
        }

        if (!(LASTHALF && i == 4)) {
            const bf16x8* Rv = (const bf16x8*)Wrs[cur];
            const bf16x8* Ov = (const bf16x8*)OsL;
            int tt = wid;
            int ct0 = tt * 16;
            bf16x8 ao = Ov[(ct0 + r15) * 5 + q];
            int sg = q ^ (r15 & 7);
            f32x4 racc[2] = {};
#pragma unroll
            for (int fj = 0; fj < 2; ++fj)
                racc[fj] = __builtin_amdgcn_mfma_f32_16x16x32_bf16(
                    ao, Rv[(fj * 16 + r15) * 8 + sg], racc[fj], 0, 0, 0);
#pragma unroll
            for (int fj = 0; fj < 2; ++fj)
#pragma unroll
                for (int rr = 0; rr < 4; ++rr) {
                    int col = ct0 + q * 4 + rr;
                    int ch  = fj * 16 + r15;
                    if (c0 + col - H >= 0)
                        resL[col * 36 + ch] += racc[fj][rr];
                }
        }
    }

    if (!LASTHALF) {
        __syncthreads();
        int ch = tid >> 3, t4 = (tid & 7) * 4;
#pragma unroll
        for (int j = 0; j < 4; ++j) {
            int t = r + S * (c0 + t4 + j);
            res_out[((size_t)(b * 32) + ch) * Lc + t] = resL[(H + t4 + j) * 36 + ch];
        }
    }
}

// ============================================================
// G1: bf16 MFMA GEMM, 128x128 tile (unchanged)
// ============================================================
template <bool RELU_OUT, bool OUT_BF16, int NKT>
__global__ __launch_bounds__(256) void gemm_mfma(
    const __hip_bfloat16* __restrict__ X,
    const __hip_bfloat16* __restrict__ W,
    const float* __restrict__ bias,
    void* __restrict__ Y,
    int M, int MB)
{
    constexpr int K = NKT * 64;
    __shared__ __align__(16) char smem[65536];
    i32x4* Xs0 = (i32x4*)smem;
    i32x4* Ws0 = (i32x4*)(smem + 16384);
    i32x4* Xs1 = (i32x4*)(smem + 32768);
    i32x4* Ws1 = (i32x4*)(smem + 49152);

    int nwg  = gridDim.x;
    int orig = blockIdx.x;
    int q8 = nwg >> 3, r8 = nwg & 7;
    int xcd = orig & 7, loc = orig >> 3;
    int wgid = (xcd < r8 ? xcd * (q8 + 1) : r8 * (q8 + 1) + (xcd - r8) * q8) + loc;
    int mi  = wgid % MB;
    int byy = wgid / MB;
    int b   = byy / TTILES;
    int t0  = (byy % TTILES) * 128;
    int m0  = mi * 128;

    int tid = threadIdx.x;
    int lane = tid & 63, wid = tid >> 6;
    int wy = wid >> 1, wx = wid & 1;
    int r15 = lane & 15, q = lane >> 4;

    int subrow = lane >> 3;
    int g      = (lane & 7) ^ subrow;
    const __hip_bfloat16* xp[4];
    const __hip_bfloat16* wp[4];
#pragma unroll
    for (int i = 0; i < 4; ++i) {
        int r = wid * 32 + i * 8 + subrow;
        int xrow = t0 + r; if (xrow > TGT - 1) xrow = TGT - 1;
        xp[i] = X + ((size_t)(b * TGT + xrow)) * K + g * 8;
        wp[i] = W + ((size_t)(m0 + r)) * K + g * 8;
    }

    f32x4 acc[4][4] = {};

#define STAGE(XB, WB)                                                          \
    {                                                                          \
        _Pragma("unroll")                                                      \
        for (int i = 0; i < 4; ++i) {                                          \
            __builtin_amdgcn_global_load_lds((as1v)(void*)xp[i],               \
                (as3v)(void*)&XB[(wid * 4 + i) * 64], 16, 0, 0);               \
            __builtin_amdgcn_global_load_lds((as1v)(void*)wp[i],               \
                (as3v)(void*)&WB[(wid * 4 + i) * 64], 16, 0, 0);               \
            xp[i] += 64; wp[i] += 64;                                          \
        }                                                                      \
    }

    auto compute = [&](const i32x4* Xb, const i32x4* Wb) {
        const bf16x8* Xv = (const bf16x8*)Xb;
        const bf16x8* Wv = (const bf16x8*)Wb;
#pragma unroll
        for (int kk = 0; kk < 2; ++kk) {
            int sg = (kk * 4 + q) ^ (r15 & 7);
            bf16x8 af[4], bw[4];
#pragma unroll
            for (int ft = 0; ft < 4; ++ft)
                af[ft] = Xv[(wy * 64 + ft * 16 + r15) * 8 + sg];
#pragma unroll
            for (int fj = 0; fj < 4; ++fj)
                bw[fj] = Wv[(wx * 64 + fj * 16 + r15) * 8 + sg];
#pragma unroll
            for (int ft = 0; ft < 4; ++ft)
#pragma unroll
                for (int fj = 0; fj < 4; ++fj)
                    acc[ft][fj] = __builtin_amdgcn_mfma_f32_16x16x32_bf16(
                        af[ft], bw[fj], acc[ft][fj], 0, 0, 0);
        }
    };

    STAGE(Xs0, Ws0);

#pragma unroll
    for (int kt2 = 0; kt2 < NKT; kt2 += 2) {
        STAGE(Xs1, Ws1);
        asm volatile("s_waitcnt vmcnt(8)" ::: "memory");
        __builtin_amdgcn_s_barrier();
        __builtin_amdgcn_sched_barrier(0);
        __builtin_amdgcn_s_setprio(1);
        compute(Xs0, Ws0);
        __builtin_amdgcn_s_setprio(0);
        __builtin_amdgcn_sched_barrier(0);
        __builtin_amdgcn_s_barrier();

        if (kt2 + 2 < NKT) {
            STAGE(Xs0, Ws0);
            asm volatile("s_waitcnt vmcnt(8)" ::: "memory");
        } else {
            asm volatile("s_waitcnt vmcnt(0)" ::: "memory");
        }
        __builtin_amdgcn_s_barrier();
        __builtin_amdgcn_sched_barrier(0);
        __builtin_amdgcn_s_setprio(1);
        compute(Xs1, Ws1);
        __builtin_amdgcn_s_setprio(0);
        __builtin_amdgcn_sched_barrier(0);
        __builtin_amdgcn_s_barrier();
    }
#undef STAGE

    if (OUT_BF16) {
        __hip_bfloat16* Eb = (__hip_bfloat16*)smem;  // [128][136] padded
#pragma unroll
        for (int ft = 0; ft < 4; ++ft) {
#pragma unroll
            for (int r = 0; r < 4; ++r) {
                int tl = wy * 64 + ft * 16 + q * 4 + r;
#pragma unroll
                for (int fj = 0; fj < 4; ++fj) {
                    int ml = wx * 64 + fj * 16 + r15;
                    float v = acc[ft][fj][r];
                    if (bias) v += bias[m0 + ml];
                    if (RELU_OUT) v = fmaxf(v, 0.f);
                    Eb[tl * 136 + ml] = __float2bfloat16(v);
                }
            }
        }
        __syncthreads();
        int row = tid >> 1, half = tid & 1;
        int t = t0 + row;
        if (t < TGT) {
            __hip_bfloat16* dst = (__hip_bfloat16*)Y + ((size_t)(b * TGT + t)) * M + m0 + half * 64;
            const __hip_bfloat16* src = Eb + row * 136 + half * 64;
#pragma unroll
            for (int k = 0; k < 8; ++k)
                ((i32x4*)dst)[k] = ((const i32x4*)src)[k];
        }
    } else {
#pragma unroll
        for (int ft = 0; ft < 4; ++ft) {
#pragma unroll
            for (int r = 0; r < 4; ++r) {
                int t = t0 + wy * 64 + ft * 16 + q * 4 + r;
                if (t < TGT) {
                    size_t rowoff = ((size_t)(b * TGT + t)) * M;
#pragma unroll
                    for (int fj = 0; fj < 4; ++fj) {
                        int m = m0 + wx * 64 + fj * 16 + r15;
                        float v = acc[ft][fj][r];
                        if (bias) v += bias[m];
                        if (RELU_OUT) v = fmaxf(v, 0.f);
                        ((float*)Y)[rowoff + m] = v;
                    }
                }
            }
        }
    }
}

// ============================================================
// FUSED G2+G3 (unchanged from R16)
// ============================================================
__global__ __launch_bounds__(512) void gemm_fused23(
    const __hip_bfloat16* __restrict__ X,    // finalT [B*TGT][1024]
    const __hip_bfloat16* __restrict__ W2,   // [512][1024]
    const float* __restrict__ b1,            // [512]
    const __hip_bfloat16* __restrict__ W3,   // [256][512]
    const float* __restrict__ b2,            // [256]
    float* __restrict__ Y)                   // [B*TGT][256]
{
    __shared__ __align__(16) char smem[153600];
    i32x4* Xs[2] = { (i32x4*)smem, (i32x4*)(smem + 8192) };
    i32x4* Ws[2] = { (i32x4*)(smem + 16384), (i32x4*)(smem + 81920) };
    __hip_bfloat16* Hs = (__hip_bfloat16*)(smem + 16384);
    i32x4* W3s[2] = { (i32x4*)(smem + 88064), (i32x4*)(smem + 120832) };

    int nwg  = gridDim.x;
    int orig = blockIdx.x;
    int q8 = nwg >> 3, r8 = nwg & 7;
    int xcd = orig & 7, loc = orig >> 3;
    int wgid = (xcd < r8 ? xcd * (q8 + 1) : r8 * (q8 + 1) + (xcd - r8) * q8) + loc;
    int b  = wgid / T64;
    int t0 = (wgid % T64) * 64;

    int tid = threadIdx.x;
    int lane = tid & 63, wid = tid >> 6;
    int r15 = lane & 15, q = lane >> 4;
    int subrow = lane >> 3;
    int g      = (lane & 7) ^ subrow;

    int xr = wid * 8 + subrow;
    int xrow = t0 + xr; if (xrow > TGT - 1) xrow = TGT - 1;
    const __hip_bfloat16* xp = X + ((size_t)(b * TGT + xrow)) * SCc + g * 8;
    const __hip_bfloat16* wp[8];
#pragma unroll
    for (int i = 0; i < 8; ++i)
        wp[i] = W2 + ((size_t)((wid * 8 + i) * 8 + subrow)) * SCc + g * 8;

    f32x4 acc[4][4] = {};

#define STAGEA(bi)                                                             \
    {                                                                          \
        __builtin_amdgcn_global_load_lds((as1v)(void*)xp,                      \
            (as3v)(void*)&Xs[bi][wid * 64], 16, 0, 0);                         \
        xp += 64;                                                              \
        _Pragma("unroll")                                                      \
        for (int i = 0; i < 8; ++i) {                                          \
            __builtin_amdgcn_global_load_lds((as1v)(void*)wp[i],               \
                (as3v)(void*)&Ws[bi][(wid * 8 + i) * 64], 16, 0, 0);           \
            wp[i] += 64;                                                       \
        }                                                                      \
    }

    auto computeA = [&](const i32x4* Xb, const i32x4* Wb) {
        const bf16x8* Xv = (const bf16x8*)Xb;
        const bf16x8* Wv = (const bf16x8*)Wb;
#pragma unroll
        for (int kk = 0; kk < 2; ++kk) {
            int sg = (kk * 4 + q) ^ (r15 & 7);
            bf16x8 af[4], bw[4];
#pragma unroll
            for (int ft = 0; ft < 4; ++ft)
                af[ft] = Xv[(ft * 16 + r15) * 8 + sg];
#pragma unroll
            for (int fj = 0; fj < 4; ++fj)
                bw[fj] = Wv[(wid * 64 + fj * 16 + r15) * 8 + sg];
#pragma unroll
            for (int ft = 0; ft < 4; ++ft)
#pragma unroll
                for (int fj = 0; fj < 4; ++fj)
                    acc[ft][fj] = __builtin_amdgcn_mfma_f32_16x16x32_bf16(
                        af[ft], bw[fj], acc[ft][fj], 0, 0, 0);
        }
    };

    STAGEA(0);
#pragma unroll
    for (int kt = 0; kt < 16; ++kt) {
        const int cur = kt & 1;
        if (kt + 1 < 16) {
            STAGEA(cur ^ 1);
            asm volatile("s_waitcnt vmcnt(9)" ::: "memory");
        } else {
            asm volatile("s_waitcnt vmcnt(0)" ::: "memory");
        }
        __builtin_amdgcn_s_barrier();
        __builtin_amdgcn_sched_barrier(0);
        __builtin_amdgcn_s_setprio(1);
        computeA(Xs[cur], Ws[cur]);
        __builtin_amdgcn_s_setprio(0);
        __builtin_amdgcn_sched_barrier(0);
        __builtin_amdgcn_s_barrier();
    }
#undef STAGEA

#pragma unroll
    for (int ft = 0; ft < 4; ++ft) {
#pragma unroll
        for (int r = 0; r < 4; ++r) {
            int tl = ft * 16 + q * 4 + r;
#pragma unroll
            for (int fj = 0; fj < 4; ++fj) {
                int m = wid * 64 + fj * 16 + r15;
                float v = acc[ft][fj][r] + b1[m];
                v = fmaxf(v, 0.f);
                Hs[tl * 520 + m] = __float2bfloat16(v);
            }
        }
    }

    const __hip_bfloat16* w3p[4];
#pragma unroll
    for (int i = 0; i < 4; ++i)
        w3p[i] = W3 + ((size_t)((wid * 4 + i) * 8 + subrow)) * ECc + g * 8;

#define STAGEB(bi)                                                             \
    {                                                                          \
        _Pragma("unroll")                                                      \
        for (int i = 0; i < 4; ++i) {                                          \
            __builtin_amdgcn_global_load_lds((as1v)(void*)w3p[i],              \
                (as3v)(void*)&W3s[bi][(wid * 4 + i) * 64], 16, 0, 0);          \
            w3p[i] += 64;                                                      \
        }                                                                      \
    }

    STAGEB(0);
    __syncthreads();

    f32x4 accB[4][2] = {};

#pragma unroll
    for (int kt = 0; kt < 8; ++kt) {
        const int cur = kt & 1;
        if (kt + 1 < 8) {
            STAGEB(cur ^ 1);
            asm volatile("s_waitcnt vmcnt(4)" ::: "memory");
        } else {
            asm volatile("s_waitcnt vmcnt(0)" ::: "memory");
        }
        __builtin_amdgcn_s_barrier();
        __builtin_amdgcn_sched_barrier(0);
        __builtin_amdgcn_s_setprio(1);
        {
            const bf16x8* Wv = (const bf16x8*)W3s[cur];
#pragma unroll
            for (int kk = 0; kk < 2; ++kk) {
                int gk = kt * 8 + kk * 4 + q;
                int sg = (kk * 4 + q) ^ (r15 & 7);
                bf16x8 af[4], bw[2];
#pragma unroll
                for (int ft = 0; ft < 4; ++ft)
                    af[ft] = *(const bf16x8*)&Hs[(ft * 16 + r15) * 520 + gk * 8];
#pragma unroll
                for (int fj = 0; fj < 2; ++fj)
                    bw[fj] = Wv[(wid * 32 + fj * 16 + r15) * 8 + sg];
#pragma unroll
                for (int ft = 0; ft < 4; ++ft)
#pragma unroll
                    for (int fj = 0; fj < 2; ++fj)
                        accB[ft][fj] = __builtin_amdgcn_mfma_f32_16x16x32_bf16(
                            af[ft], bw[fj], accB[ft][fj], 0, 0, 0);
            }
        }
        __builtin_amdgcn_s_setprio(0);
        __builtin_amdgcn_sched_barrier(0);
        __builtin_amdgcn_s_barrier();
    }
#undef STAGEB

#pragma unroll
    for (int ft = 0; ft < 4; ++ft) {
#pragma unroll
        for (int r = 0; r < 4; ++r) {
            int t = t0 + ft * 16 + q * 4 + r;
            if (t < TGT) {
                size_t rowoff = ((size_t)(b * TGT + t)) * OCc;
#pragma unroll
                for (int fj = 0; fj < 2; ++fj) {
                    int m = wid * 32 + fj * 16 + r15;
                    Y[rowoff + m] = accB[ft][fj][r] + b2[m];
                }
            }
        }
    }
}

// ============================================================
extern "C" void kernel_launch(void* const* d_in, const int* in_sizes, int n_in,
                              void* d_out, int out_size, void* d_ws, size_t ws_size,
                              hipStream_t stream)
{
    const float* inputs   = (const float*)d_in[0];
    const float* cond     = (const float*)d_in[1];
    const float* input_w  = (const float*)d_in[2];
    const float* filter_w = (const float*)d_in[3];
    const float* gate_w   = (const float*)d_in[4];
    const float* res_w    = (const float*)d_in[5];
    const float* split_w  = (const float*)d_in[6];
    const float* gcf_w    = (const float*)d_in[7];
    const float* gcs_w    = (const float*)d_in[8];
    const float* f1_w     = (const float*)d_in[9];
    const float* f1_b     = (const float*)d_in[10];
    const float* f2_w     = (const float*)d_in[11];
    const float* f2_b     = (const float*)d_in[12];
    float* out = (float*)d_out;

    char* wsb = (char*)d_ws;
    const size_t RES_B   = (size_t)Bc * RCc * Lc * 4;
    const size_t OUTS_B  = (size_t)Bc * TGT * KTOT * 2;
    const size_t FIN_B   = (size_t)Bc * TGT * SCc * 2;
    const size_t W1_B    = (size_t)SCc * KTOT * 2;
    const size_t W2_B    = (size_t)ECc * SCc * 2;
    const size_t W3_B    = (size_t)OCc * ECc * 2;
    const size_t WFG_B   = (size_t)NL * 64 * 64 * 2;
    const size_t WR_B    = (size_t)NL * 32 * 64 * 2;

    float* res0              = (float*)wsb;                   size_t off = RES_B;
    float* res1              = (float*)(wsb + off);           off += RES_B;
    __hip_bfloat16* outsT    = (__hip_bfloat16*)(wsb + off);  off += OUTS_B;
    __hip_bfloat16* finalT   = (__hip_bfloat16*)(wsb + off);  off += FIN_B;
    __hip_bfloat16* Wp1      = (__hip_bfloat16*)(wsb + off);  off += W1_B;
    __hip_bfloat16* Wp2      = (__hip_bfloat16*)(wsb + off);  off += W2_B;
    __hip_bfloat16* Wp3      = (__hip_bfloat16*)(wsb + off);  off += W3_B;
    __hip_bfloat16* wfgp     = (__hip_bfloat16*)(wsb + off);  off += WFG_B;
    __hip_bfloat16* wrp      = (__hip_bfloat16*)(wsb + off);  off += WR_B;

    // prep: packs + input conv in one node
    {
        const int NTOT = SCc * KTOT + ECc * SCc + OCc * ECc + NL * 64 * 64;
        const int npack = (NTOT + 255) / 256;
        prep_kernel<<<npack + Bc * 128, 256, 0, stream>>>(
            inputs, input_w, res0,
            split_w, f1_w, f2_w, filter_w, gate_w, res_w,
            Wp1, Wp2, Wp3, wfgp, wrp, npack);
    }

    float* rin = res0;
    float* rout = res1;
    const dim3 lgrid(Lc / 32, Bc);   // 256 tiles x B = 512 blocks
    const dim3 sgrid(256, Bc);       // 32 residues x 8 segments x B

    layer_group5<<<lgrid, 256, 0, stream>>>(
        rin, rout, outsT, wfgp, wrp, cond, gcf_w, gcs_w, 0);
    { float* t = rin; rin = rout; rout = t; }
    layer_groupS<false><<<sgrid, 256, 0, stream>>>(
        rin, rout, outsT, wfgp, wrp, cond, gcf_w, gcs_w, 5);
    { float* t = rin; rin = rout; rout = t; }
    layer_group5<<<lgrid, 256, 0, stream>>>(
        rin, rout, outsT, wfgp, wrp, cond, gcf_w, gcs_w, 10);
    { float* t = rin; rin = rout; rout = t; }
    layer_groupS<true><<<sgrid, 256, 0, stream>>>(
        rin, rout, outsT, wfgp, wrp, cond, gcf_w, gcs_w, 15);

    // G1: finalT = relu( outsT(12292x640) @ Wp1^T )   -> bf16 [t][1024]
    gemm_mfma<true, true, 10><<<(SCc / 128) * Bc * TTILES, 256, 0, stream>>>(
        outsT, Wp1, nullptr, finalT, SCc, SCc / 128);

    // G2+G3 fused: out = (relu(finalT@Wp2^T + f1_b)) @ Wp3^T + f2_b
    gemm_fused23<<<Bc * T64, 512, 0, stream>>>(
        finalT, Wp2, f1_b, Wp3, f2_b, out);
}

// Round 18
// 163.139 us; speedup vs baseline: 1.0305x; 1.0305x over previous
//
#include <hip/hip_runtime.h>
#include <hip/hip_bf16.h>
#include <cstddef>

// ---- problem constants ----
#define Bc   2
#define Lc   8192
#define TGT  6146          // L - RF, RF = 2046
#define NL   20            // layers
#define RCc  32
#define DCc  32
#define SCc  1024
#define ECc  512
#define OCc  256
#define KTOT (NL * DCc)    // 640
#define TTILES 49          // ceil(TGT/128)
#define T64   97           // ceil(TGT/64)

typedef __attribute__((ext_vector_type(4))) float f32x4;
typedef __attribute__((ext_vector_type(8))) short bf16x8;
typedef __attribute__((ext_vector_type(4))) int i32x4;
typedef __attribute__((ext_vector_type(2))) int i32x2;

typedef __attribute__((address_space(1))) void* as1v;
typedef __attribute__((address_space(3))) void* as3v;

__device__ inline bf16x8 cvt8(const float4* p) {
    float4 a = p[0], b = p[1];
    union { bf16x8 v; __hip_bfloat16 h[8]; } u;
    u.h[0] = __float2bfloat16(a.x); u.h[1] = __float2bfloat16(a.y);
    u.h[2] = __float2bfloat16(a.z); u.h[3] = __float2bfloat16(a.w);
    u.h[4] = __float2bfloat16(b.x); u.h[5] = __float2bfloat16(b.y);
    u.h[6] = __float2bfloat16(b.z); u.h[7] = __float2bfloat16(b.w);
    return u.v;
}

// ============================================================
// prep kernel: weight packs (blocks [0,npack)) + input 1x1 conv
// ============================================================
__global__ __launch_bounds__(256) void prep_kernel(
    const float* __restrict__ x,        // [B][256][L]
    const float* __restrict__ iw,       // [32][256]
    float* __restrict__ res_out,        // [B][32][L]
    const float* __restrict__ split_w,
    const float* __restrict__ f1_w,
    const float* __restrict__ f2_w,
    const float* __restrict__ filt,
    const float* __restrict__ gate,
    const float* __restrict__ resw,
    __hip_bfloat16* __restrict__ Wp1,
    __hip_bfloat16* __restrict__ Wp2,
    __hip_bfloat16* __restrict__ Wp3,
    __hip_bfloat16* __restrict__ wfgp,
    __hip_bfloat16* __restrict__ wrp,
    int npack)
{
    __shared__ float ws[32][256];
    __shared__ float xs[64][64];
    int tid = threadIdx.x;

    if ((int)blockIdx.x < npack) {
        int idx = blockIdx.x * 256 + tid;
        const int N1 = SCc * KTOT, N2 = ECc * SCc, N3 = OCc * ECc, N4 = NL * 64 * 64;
        if (idx < N1) {
            int m = idx / KTOT, k = idx % KTOT;
            int i = k >> 5, c = k & 31;
            Wp1[idx] = __float2bfloat16(split_w[((size_t)i * SCc + m) * DCc + c]);
            return;
        }
        idx -= N1;
        if (idx < N2) { Wp2[idx] = __float2bfloat16(f1_w[idx]); return; }
        idx -= N2;
        if (idx < N3) { Wp3[idx] = __float2bfloat16(f2_w[idx]); return; }
        idx -= N3;
        if (idx < N4) {
            int li = idx / 4096, r = idx % 4096;
            int m = r >> 6, k = r & 63;
            int tap = k >> 5, ic = k & 31;
            float v = (m < 32) ? filt[(size_t)li * 2048 + (m * 32 + ic) * 2 + tap]
                               : gate[(size_t)li * 2048 + ((m - 32) * 32 + ic) * 2 + tap];
            int slot = (k >> 3) ^ (m & 7);
            wfgp[((size_t)li * 64 + m) * 64 + slot * 8 + (k & 7)] = __float2bfloat16(v);
            if (r < 2048) {
                int m2 = r >> 6;
                float v2 = (k < 32) ? resw[(size_t)li * 1024 + m2 * 32 + k] : 0.f;
                wrp[((size_t)li * 32 + m2) * 64 + slot * 8 + (k & 7)] = __float2bfloat16(v2);
            }
        }
        return;
    }

    // ---- input conv part ----
    int bid = blockIdx.x - npack;
    int b   = bid >> 7;
    int t0  = (bid & 127) * 64;

    for (int idx = tid; idx < 32 * 256; idx += 256)
        ws[idx >> 8][idx & 255] = iw[idx];

    int tl = tid & 63, qq = tid >> 6, oc0 = qq * 8;
    float acc[8] = {};

    for (int icc = 0; icc < 4; ++icc) {
        __syncthreads();
        for (int idx = tid; idx < 64 * 64; idx += 256) {
            int icl = idx >> 6, tll = idx & 63;
            xs[icl][tll] = x[((size_t)b * 256 + icc * 64 + icl) * Lc + t0 + tll];
        }
        __syncthreads();
        for (int icl = 0; icl < 64; icl += 4) {
            float x0 = xs[icl][tl], x1 = xs[icl + 1][tl];
            float x2 = xs[icl + 2][tl], x3 = xs[icl + 3][tl];
#pragma unroll
            for (int j = 0; j < 8; ++j) {
                const float4 w4 = *(const float4*)&ws[oc0 + j][icc * 64 + icl];
                acc[j] += w4.x * x0 + w4.y * x1 + w4.z * x2 + w4.w * x3;
            }
        }
    }
#pragma unroll
    for (int j = 0; j < 8; ++j)
        res_out[((size_t)b * 32 + oc0 + j) * Lc + t0 + tl] = acc[j];
}

// ============================================================
// grouped layers d=1..16 (stride-1), W=96, 512 thr (R16 config)
// ============================================================
__global__ __launch_bounds__(512) void layer_group5(
    const float* __restrict__ res_in,
    float* __restrict__ res_out,
    __hip_bfloat16* __restrict__ outsT,
    const __hip_bfloat16* __restrict__ wfgp,
    const __hip_bfloat16* __restrict__ wrp,
    const float* __restrict__ cond,
    const float* __restrict__ gcf_w,
    const float* __restrict__ gcs_w,
    int l0)
{
    constexpr int W = 96, H = 32, NT = 6;
    __shared__ __align__(16) float resL[W * 36];
    __shared__ __align__(16) unsigned short OsL[W * 40];
    __shared__ __align__(16) i32x4 Wf[2][64 * 8];
    __shared__ __align__(16) i32x4 Wrs[2][32 * 8];

    int tid  = threadIdx.x;
    int b    = blockIdx.y;
    int t0   = blockIdx.x * 64;
    int lane = tid & 63, wid = tid >> 6;
    int r15  = lane & 15, q = lane >> 4;

    const float* rb = res_in + (size_t)b * 32 * Lc;
    for (int idx = tid; idx < W * 32; idx += 512) {
        int ch = idx / W, tl = idx % W;
        int tg = t0 - H + tl;
        resL[tl * 36 + ch] = (tg >= 0) ? rb[(size_t)ch * Lc + tg] : 0.f;
    }

    auto issueW = [&](int bufi, int li2) {
        const __hip_bfloat16* wfg = wfgp + (size_t)li2 * 4096;
        const __hip_bfloat16* wrl = wrp  + (size_t)li2 * 2048;
        __builtin_amdgcn_global_load_lds(
            (as1v)(void*)((const i32x4*)wfg + wid * 64 + lane),
            (as3v)(void*)&Wf[bufi][wid * 64], 16, 0, 0);
        if (wid < 4)
            __builtin_amdgcn_global_load_lds(
                (as1v)(void*)((const i32x4*)wrl + wid * 64 + lane),
                (as3v)(void*)&Wrs[bufi][wid * 64], 16, 0, 0);
    };
    issueW(0, l0);

#pragma unroll
    for (int i = 0; i < 5; ++i) {
        const int cur = i & 1;
        int li = l0 + i;
        int d  = 1 << i;

        float gf = 0.f, gg = 0.f;
#pragma unroll
        for (int c = 0; c < 5; ++c) {
            gf += gcf_w[li * 5 + c] * cond[b * 5 + c];
            gg += gcs_w[li * 5 + c] * cond[b * 5 + c];
        }
        __syncthreads();
        if (i + 1 < 5) issueW(cur ^ 1, li + 1);

        const bf16x8* Wv = (const bf16x8*)Wf[cur];
        for (int tt = wid; tt < NT; tt += 8) {
            int ct0 = tt * 16;
            int srow0 = ct0 + r15 - d; if (srow0 < 0) srow0 = 0;
            int srow1 = ct0 + r15;
            bf16x8 a0 = cvt8((const float4*)&resL[srow0 * 36 + q * 8]);
            bf16x8 a1 = cvt8((const float4*)&resL[srow1 * 36 + q * 8]);
            int sg0 = q ^ (r15 & 7), sg1 = (4 + q) ^ (r15 & 7);
            f32x4 acc[4] = {};
#pragma unroll
            for (int fj = 0; fj < 4; ++fj)
                acc[fj] = __builtin_amdgcn_mfma_f32_16x16x32_bf16(
                    a0, Wv[(fj * 16 + r15) * 8 + sg0], acc[fj], 0, 0, 0);
#pragma unroll
            for (int fj = 0; fj < 4; ++fj)
                acc[fj] = __builtin_amdgcn_mfma_f32_16x16x32_bf16(
                    a1, Wv[(fj * 16 + r15) * 8 + sg1], acc[fj], 0, 0, 0);
#pragma unroll
            for (int fj = 0; fj < 2; ++fj) {
#pragma unroll
                for (int r = 0; r < 4; ++r) {
                    float F = acc[fj][r] + gf;
                    float G = acc[fj + 2][r] + gg;
                    float th  = 1.f - 2.f / (__expf(2.f * F) + 1.f);
                    float sgm = 1.f / (1.f + __expf(-G));
                    float o   = th * sgm;
                    int col = ct0 + q * 4 + r;
                    int ch  = fj * 16 + r15;
                    __hip_bfloat16 ob = __float2bfloat16(o);
                    OsL[col * 40 + ch] = *(unsigned short*)&ob;
                }
            }
        }
        __syncthreads();

        {
            int row = tid >> 3, chunk = tid & 7;
            int tg = t0 + row;
            if (tg >= Lc - TGT) {
                i32x2 v = *(const i32x2*)&OsL[(H + row) * 40 + chunk * 4];
                *(i32x2*)(outsT + ((size_t)(b * TGT + tg - (Lc - TGT))) * KTOT
                          + li * 32 + chunk * 4) = v;
            }
        }

        const bf16x8* Rv = (const bf16x8*)Wrs[cur];
        const bf16x8* Ov = (const bf16x8*)OsL;
        for (int tt = wid; tt < NT; tt += 8) {
            int ct0 = tt * 16;
            bf16x8 ao = Ov[(ct0 + r15) * 5 + q];
            int sg = q ^ (r15 & 7);
            f32x4 racc[2] = {};
#pragma unroll
            for (int fj = 0; fj < 2; ++fj)
                racc[fj] = __builtin_amdgcn_mfma_f32_16x16x32_bf16(
                    ao, Rv[(fj * 16 + r15) * 8 + sg], racc[fj], 0, 0, 0);
#pragma unroll
            for (int fj = 0; fj < 2; ++fj)
#pragma unroll
                for (int r = 0; r < 4; ++r) {
                    int col = ct0 + q * 4 + r;
                    int ch  = fj * 16 + r15;
                    if (t0 + col - H >= 0)
                        resL[col * 36 + ch] += racc[fj][r];
                }
        }
    }
    __syncthreads();

    {
        int ch = tid >> 4, t4 = (tid & 15) * 4;
        float v[4];
#pragma unroll
        for (int j = 0; j < 4; ++j) v[j] = resL[(H + t4 + j) * 36 + ch];
        float* ro = res_out + ((size_t)(b * 32) + ch) * Lc + t0 + t4;
        *(float4*)ro = make_float4(v[0], v[1], v[2], v[3]);
    }
}

// ============================================================
// strided grouped layers d=32..512 (stride-32 residues), R16
// ============================================================
template <bool LASTHALF>
__global__ __launch_bounds__(512) void layer_groupS(
    const float* __restrict__ res_in,
    float* __restrict__ res_out,
    __hip_bfloat16* __restrict__ outsT,
    const __hip_bfloat16* __restrict__ wfgp,
    const __hip_bfloat16* __restrict__ wrp,
    const float* __restrict__ cond,
    const float* __restrict__ gcf_w,
    const float* __restrict__ gcs_w,
    int l0)
{
    constexpr int W = 96, H = 32, NT = 6, S = 32;
    __shared__ __align__(16) float resL[W * 36];
    __shared__ __align__(16) unsigned short OsL[W * 40];
    __shared__ __align__(16) i32x4 Wf[2][64 * 8];
    __shared__ __align__(16) i32x4 Wrs[2][32 * 8];

    int tid  = threadIdx.x;
    int b    = blockIdx.y;
    int r    = blockIdx.x & 31;
    int c0   = (blockIdx.x >> 5) * 64;
    int lane = tid & 63, wid = tid >> 6;
    int r15  = lane & 15, q = lane >> 4;

    const float* rb = res_in + (size_t)b * 32 * Lc;
    for (int idx = tid; idx < W * 32; idx += 512) {
        int ch = idx / W, col = idx % W;
        int cj = c0 + col - H;
        resL[col * 36 + ch] = (cj >= 0) ? rb[(size_t)ch * Lc + r + S * cj] : 0.f;
    }

    auto issueW = [&](int bufi, int li2) {
        const __hip_bfloat16* wfg = wfgp + (size_t)li2 * 4096;
        const __hip_bfloat16* wrl = wrp  + (size_t)li2 * 2048;
        __builtin_amdgcn_global_load_lds(
            (as1v)(void*)((const i32x4*)wfg + wid * 64 + lane),
            (as3v)(void*)&Wf[bufi][wid * 64], 16, 0, 0);
        if (wid < 4)
            __builtin_amdgcn_global_load_lds(
                (as1v)(void*)((const i32x4*)wrl + wid * 64 + lane),
                (as3v)(void*)&Wrs[bufi][wid * 64], 16, 0, 0);
    };
    issueW(0, l0);

#pragma unroll
    for (int i = 0; i < 5; ++i) {
        const int cur = i & 1;
        int li = l0 + i;
        int dc = 1 << i;

        float gf = 0.f, gg = 0.f;
#pragma unroll
        for (int c = 0; c < 5; ++c) {
            gf += gcf_w[li * 5 + c] * cond[b * 5 + c];
            gg += gcs_w[li * 5 + c] * cond[b * 5 + c];
        }
        __syncthreads();
        if (i + 1 < 5) issueW(cur ^ 1, li + 1);

        const bf16x8* Wv = (const bf16x8*)Wf[cur];
        for (int tt = wid; tt < NT; tt += 8) {
            int ct0 = tt * 16;
            int srow0 = ct0 + r15 - dc; if (srow0 < 0) srow0 = 0;
            int srow1 = ct0 + r15;
            bf16x8 a0 = cvt8((const float4*)&resL[srow0 * 36 + q * 8]);
            bf16x8 a1 = cvt8((const float4*)&resL[srow1 * 36 + q * 8]);
            int sg0 = q ^ (r15 & 7), sg1 = (4 + q) ^ (r15 & 7);
            f32x4 acc[4] = {};
#pragma unroll
            for (int fj = 0; fj < 4; ++fj)
                acc[fj] = __builtin_amdgcn_mfma_f32_16x16x32_bf16(
                    a0, Wv[(fj * 16 + r15) * 8 + sg0], acc[fj], 0, 0, 0);
#pragma unroll
            for (int fj = 0; fj < 4; ++fj)
                acc[fj] = __builtin_amdgcn_mfma_f32_16x16x32_bf16(
                    a1, Wv[(fj * 16 + r15) * 8 + sg1], acc[fj], 0, 0, 0);
#pragma unroll
            for (int fj = 0; fj < 2; ++fj) {
#pragma unroll
                for (int rr = 0; rr < 4; ++rr) {
                    float F = acc[fj][rr] + gf;
                    float G = acc[fj + 2][rr] + gg;
                    float th  = 1.f - 2.f / (__expf(2.f * F) + 1.f);
                    float sgm = 1.f / (1.f + __expf(-G));
                    float o   = th * sgm;
                    int col = ct0 + q * 4 + rr;
                    int ch  = fj * 16 + r15;
                    __hip_bfloat16 ob = __float2bfloat16(o);
                    OsL[col * 40 + ch] = *(unsigned short*)&ob;
                }
            }
        }
        __syncthreads();

        {
            int row = tid >> 3, chunk = tid & 7;
            int t = r + S * (c0 + row);
            if (t >= Lc - TGT) {
                i32x2 v = *(const i32x2*)&OsL[(H + row) * 40 + chunk * 4];
                *(i32x2*)(outsT + ((size_t)(b * TGT + t - (Lc - TGT))) * KTOT
                          + li * 32 + chunk * 4) = v;
            }
        }

        if (!(LASTHALF && i == 4)) {
            const bf16x8* Rv = (const bf16x8*)Wrs[cur];
            const bf16x8* Ov = (const bf16x8*)OsL;
            for (int tt = wid; tt < NT; tt += 8) {
                int ct0 = tt * 16;
                bf16x8 ao = Ov[(ct0 + r15) * 5 + q];
                int sg = q ^ (r15 & 7);
                f32x4 racc[2] = {};
#pragma unroll
                for (int fj = 0; fj < 2; ++fj)
                    racc[fj] = __builtin_amdgcn_mfma_f32_16x16x32_bf16(
                        ao, Rv[(fj * 16 + r15) * 8 + sg], racc[fj], 0, 0, 0);
#pragma unroll
                for (int fj = 0; fj < 2; ++fj)
#pragma unroll
                    for (int rr = 0; rr < 4; ++rr) {
                        int col = ct0 + q * 4 + rr;
                        int ch  = fj * 16 + r15;
                        if (c0 + col - H >= 0)
                            resL[col * 36 + ch] += racc[fj][rr];
                    }
            }
        }
    }

    if (!LASTHALF) {
        __syncthreads();
        int ch = tid >> 4, t4 = (tid & 15) * 4;
#pragma unroll
        for (int j = 0; j < 4; ++j) {
            int t = r + S * (c0 + t4 + j);
            res_out[((size_t)(b * 32) + ch) * Lc + t] = resL[(H + t4 + j) * 36 + ch];
        }
    }
}

// ============================================================
// G1: bf16 MFMA GEMM, 128t x 64m tile, 48KB dbuf (3 blocks/CU),
// counted vmcnt(6), template NKT, setprio, bijective XCD swizzle.
// Per-output K-order identical to 128x128 version -> bit-identical.
// ============================================================
template <bool RELU_OUT, int NKT>
__global__ __launch_bounds__(256) void gemm_mfma64(
    const __hip_bfloat16* __restrict__ X,
    const __hip_bfloat16* __restrict__ W,
    const float* __restrict__ bias,
    __hip_bfloat16* __restrict__ Y,
    int M, int MB)   // MB = M/64
{
    constexpr int K = NKT * 64;
    __shared__ __align__(16) char smem[49152];   // 48 KB
    i32x4* Xs0 = (i32x4*)smem;                   // 16 KB (128 x 8)
    i32x4* Ws0 = (i32x4*)(smem + 16384);         //  8 KB (64 x 8)
    i32x4* Xs1 = (i32x4*)(smem + 24576);
    i32x4* Ws1 = (i32x4*)(smem + 40960);

    int nwg  = gridDim.x;
    int orig = blockIdx.x;
    int q8 = nwg >> 3, r8 = nwg & 7;
    int xcd = orig & 7, loc = orig >> 3;
    int wgid = (xcd < r8 ? xcd * (q8 + 1) : r8 * (q8 + 1) + (xcd - r8) * q8) + loc;
    int mi  = wgid % MB;
    int byy = wgid / MB;
    int b   = byy / TTILES;
    int t0  = (byy % TTILES) * 128;
    int m0  = mi * 64;

    int tid = threadIdx.x;
    int lane = tid & 63, wid = tid >> 6;   // 4 waves: wave owns 32t x 64m
    int r15 = lane & 15, q = lane >> 4;

    int subrow = lane >> 3;
    int g      = (lane & 7) ^ subrow;
    const __hip_bfloat16* xp[4];
    const __hip_bfloat16* wp[2];
#pragma unroll
    for (int i = 0; i < 4; ++i) {
        int r = wid * 32 + i * 8 + subrow;
        int xrow = t0 + r; if (xrow > TGT - 1) xrow = TGT - 1;
        xp[i] = X + ((size_t)(b * TGT + xrow)) * K + g * 8;
    }
#pragma unroll
    for (int i = 0; i < 2; ++i) {
        int r = wid * 16 + i * 8 + subrow;
        wp[i] = W + ((size_t)(m0 + r)) * K + g * 8;
    }

    f32x4 acc[2][4] = {};   // [t-frag(2x16)][m-frag(4x16)]

#define STAGE(XB, WB)                                                          \
    {                                                                          \
        _Pragma("unroll")                                                      \
        for (int i = 0; i < 4; ++i) {                                          \
            __builtin_amdgcn_global_load_lds((as1v)(void*)xp[i],               \
                (as3v)(void*)&XB[(wid * 4 + i) * 64], 16, 0, 0);               \
            xp[i] += 64;                                                       \
        }                                                                      \
        _Pragma("unroll")                                                      \
        for (int i = 0; i < 2; ++i) {                                          \
            __builtin_amdgcn_global_load_lds((as1v)(void*)wp[i],               \
                (as3v)(void*)&WB[(wid * 2 + i) * 64], 16, 0, 0);               \
            wp[i] += 64;                                                       \
        }                                                                      \
    }

    auto compute = [&](const i32x4* Xb, const i32x4* Wb) {
        const bf16x8* Xv = (const bf16x8*)Xb;
        const bf16x8* Wv = (const bf16x8*)Wb;
#pragma unroll
        for (int kk = 0; kk < 2; ++kk) {
            int sg = (kk * 4 + q) ^ (r15 & 7);
            bf16x8 af[2], bw[4];
#pragma unroll
            for (int ft = 0; ft < 2; ++ft)
                af[ft] = Xv[(wid * 32 + ft * 16 + r15) * 8 + sg];
#pragma unroll
            for (int fj = 0; fj < 4; ++fj)
                bw[fj] = Wv[(fj * 16 + r15) * 8 + sg];
#pragma unroll
            for (int ft = 0; ft < 2; ++ft)
#pragma unroll
                for (int fj = 0; fj < 4; ++fj)
                    acc[ft][fj] = __builtin_amdgcn_mfma_f32_16x16x32_bf16(
                        af[ft], bw[fj], acc[ft][fj], 0, 0, 0);
        }
    };

    STAGE(Xs0, Ws0);

#pragma unroll
    for (int kt2 = 0; kt2 < NKT; kt2 += 2) {
        STAGE(Xs1, Ws1);
        asm volatile("s_waitcnt vmcnt(6)" ::: "memory");
        __builtin_amdgcn_s_barrier();
        __builtin_amdgcn_sched_barrier(0);
        __builtin_amdgcn_s_setprio(1);
        compute(Xs0, Ws0);
        __builtin_amdgcn_s_setprio(0);
        __builtin_amdgcn_sched_barrier(0);
        __builtin_amdgcn_s_barrier();

        if (kt2 + 2 < NKT) {
            STAGE(Xs0, Ws0);
            asm volatile("s_waitcnt vmcnt(6)" ::: "memory");
        } else {
            asm volatile("s_waitcnt vmcnt(0)" ::: "memory");
        }
        __builtin_amdgcn_s_barrier();
        __builtin_amdgcn_sched_barrier(0);
        __builtin_amdgcn_s_setprio(1);
        compute(Xs1, Ws1);
        __builtin_amdgcn_s_setprio(0);
        __builtin_amdgcn_sched_barrier(0);
        __builtin_amdgcn_s_barrier();
    }
#undef STAGE

    // epilogue: LDS exchange -> coalesced stores (reuses smem)
    __hip_bfloat16* Eb = (__hip_bfloat16*)smem;   // [128][72] padded = 18.4 KB
#pragma unroll
    for (int ft = 0; ft < 2; ++ft) {
#pragma unroll
        for (int r = 0; r < 4; ++r) {
            int tl = wid * 32 + ft * 16 + q * 4 + r;
#pragma unroll
            for (int fj = 0; fj < 4; ++fj) {
                int ml = fj * 16 + r15;
                float v = acc[ft][fj][r];
                if (bias) v += bias[m0 + ml];
                if (RELU_OUT) v = fmaxf(v, 0.f);
                Eb[tl * 72 + ml] = __float2bfloat16(v);
            }
        }
    }
    __syncthreads();
    {
        int row = tid >> 1, half = tid & 1;
        int t = t0 + row;
        if (t < TGT) {
            __hip_bfloat16* dst = Y + ((size_t)(b * TGT + t)) * M + m0 + half * 32;
            const __hip_bfloat16* src = Eb + row * 72 + half * 32;
#pragma unroll
            for (int k = 0; k < 4; ++k)
                ((i32x4*)dst)[k] = ((const i32x4*)src)[k];
        }
    }
}

// ============================================================
// FUSED G2+G3 (unchanged from R16)
// ============================================================
__global__ __launch_bounds__(512) void gemm_fused23(
    const __hip_bfloat16* __restrict__ X,    // finalT [B*TGT][1024]
    const __hip_bfloat16* __restrict__ W2,   // [512][1024]
    const float* __restrict__ b1,            // [512]
    const __hip_bfloat16* __restrict__ W3,   // [256][512]
    const float* __restrict__ b2,            // [256]
    float* __restrict__ Y)                   // [B*TGT][256]
{
    __shared__ __align__(16) char smem[153600];
    i32x4* Xs[2] = { (i32x4*)smem, (i32x4*)(smem + 8192) };
    i32x4* Ws[2] = { (i32x4*)(smem + 16384), (i32x4*)(smem + 81920) };
    __hip_bfloat16* Hs = (__hip_bfloat16*)(smem + 16384);
    i32x4* W3s[2] = { (i32x4*)(smem + 88064), (i32x4*)(smem + 120832) };

    int nwg  = gridDim.x;
    int orig = blockIdx.x;
    int q8 = nwg >> 3, r8 = nwg & 7;
    int xcd = orig & 7, loc = orig >> 3;
    int wgid = (xcd < r8 ? xcd * (q8 + 1) : r8 * (q8 + 1) + (xcd - r8) * q8) + loc;
    int b  = wgid / T64;
    int t0 = (wgid % T64) * 64;

    int tid = threadIdx.x;
    int lane = tid & 63, wid = tid >> 6;
    int r15 = lane & 15, q = lane >> 4;
    int subrow = lane >> 3;
    int g      = (lane & 7) ^ subrow;

    int xr = wid * 8 + subrow;
    int xrow = t0 + xr; if (xrow > TGT - 1) xrow = TGT - 1;
    const __hip_bfloat16* xp = X + ((size_t)(b * TGT + xrow)) * SCc + g * 8;
    const __hip_bfloat16* wp[8];
#pragma unroll
    for (int i = 0; i < 8; ++i)
        wp[i] = W2 + ((size_t)((wid * 8 + i) * 8 + subrow)) * SCc + g * 8;

    f32x4 acc[4][4] = {};

#define STAGEA(bi)                                                             \
    {                                                                          \
        __builtin_amdgcn_global_load_lds((as1v)(void*)xp,                      \
            (as3v)(void*)&Xs[bi][wid * 64], 16, 0, 0);                         \
        xp += 64;                                                              \
        _Pragma("unroll")                                                      \
        for (int i = 0; i < 8; ++i) {                                          \
            __builtin_amdgcn_global_load_lds((as1v)(void*)wp[i],               \
                (as3v)(void*)&Ws[bi][(wid * 8 + i) * 64], 16, 0, 0);           \
            wp[i] += 64;                                                       \
        }                                                                      \
    }

    auto computeA = [&](const i32x4* Xb, const i32x4* Wb) {
        const bf16x8* Xv = (const bf16x8*)Xb;
        const bf16x8* Wv = (const bf16x8*)Wb;
#pragma unroll
        for (int kk = 0; kk < 2; ++kk) {
            int sg = (kk * 4 + q) ^ (r15 & 7);
            bf16x8 af[4], bw[4];
#pragma unroll
            for (int ft = 0; ft < 4; ++ft)
                af[ft] = Xv[(ft * 16 + r15) * 8 + sg];
#pragma unroll
            for (int fj = 0; fj < 4; ++fj)
                bw[fj] = Wv[(wid * 64 + fj * 16 + r15) * 8 + sg];
#pragma unroll
            for (int ft = 0; ft < 4; ++ft)
#pragma unroll
                for (int fj = 0; fj < 4; ++fj)
                    acc[ft][fj] = __builtin_amdgcn_mfma_f32_16x16x32_bf16(
                        af[ft], bw[fj], acc[ft][fj], 0, 0, 0);
        }
    };

    STAGEA(0);
#pragma unroll
    for (int kt = 0; kt < 16; ++kt) {
        const int cur = kt & 1;
        if (kt + 1 < 16) {
            STAGEA(cur ^ 1);
            asm volatile("s_waitcnt vmcnt(9)" ::: "memory");
        } else {
            asm volatile("s_waitcnt vmcnt(0)" ::: "memory");
        }
        __builtin_amdgcn_s_barrier();
        __builtin_amdgcn_sched_barrier(0);
        __builtin_amdgcn_s_setprio(1);
        computeA(Xs[cur], Ws[cur]);
        __builtin_amdgcn_s_setprio(0);
        __builtin_amdgcn_sched_barrier(0);
        __builtin_amdgcn_s_barrier();
    }
#undef STAGEA

#pragma unroll
    for (int ft = 0; ft < 4; ++ft) {
#pragma unroll
        for (int r = 0; r < 4; ++r) {
            int tl = ft * 16 + q * 4 + r;
#pragma unroll
            for (int fj = 0; fj < 4; ++fj) {
                int m = wid * 64 + fj * 16 + r15;
                float v = acc[ft][fj][r] + b1[m];
                v = fmaxf(v, 0.f);
                Hs[tl * 520 + m] = __float2bfloat16(v);
            }
        }
    }

    const __hip_bfloat16* w3p[4];
#pragma unroll
    for (int i = 0; i < 4; ++i)
        w3p[i] = W3 + ((size_t)((wid * 4 + i) * 8 + subrow)) * ECc + g * 8;

#define STAGEB(bi)                                                             \
    {                                                                          \
        _Pragma("unroll")                                                      \
        for (int i = 0; i < 4; ++i) {                                          \
            __builtin_amdgcn_global_load_lds((as1v)(void*)w3p[i],              \
                (as3v)(void*)&W3s[bi][(wid * 4 + i) * 64], 16, 0, 0);          \
            w3p[i] += 64;                                                      \
        }                                                                      \
    }

    STAGEB(0);
    __syncthreads();

    f32x4 accB[4][2] = {};

#pragma unroll
    for (int kt = 0; kt < 8; ++kt) {
        const int cur = kt & 1;
        if (kt + 1 < 8) {
            STAGEB(cur ^ 1);
            asm volatile("s_waitcnt vmcnt(4)" ::: "memory");
        } else {
            asm volatile("s_waitcnt vmcnt(0)" ::: "memory");
        }
        __builtin_amdgcn_s_barrier();
        __builtin_amdgcn_sched_barrier(0);
        __builtin_amdgcn_s_setprio(1);
        {
            const bf16x8* Wv = (const bf16x8*)W3s[cur];
#pragma unroll
            for (int kk = 0; kk < 2; ++kk) {
                int gk = kt * 8 + kk * 4 + q;
                int sg = (kk * 4 + q) ^ (r15 & 7);
                bf16x8 af[4], bw[2];
#pragma unroll
                for (int ft = 0; ft < 4; ++ft)
                    af[ft] = *(const bf16x8*)&Hs[(ft * 16 + r15) * 520 + gk * 8];
#pragma unroll
                for (int fj = 0; fj < 2; ++fj)
                    bw[fj] = Wv[(wid * 32 + fj * 16 + r15) * 8 + sg];
#pragma unroll
                for (int ft = 0; ft < 4; ++ft)
#pragma unroll
                    for (int fj = 0; fj < 2; ++fj)
                        accB[ft][fj] = __builtin_amdgcn_mfma_f32_16x16x32_bf16(
                            af[ft], bw[fj], accB[ft][fj], 0, 0, 0);
            }
        }
        __builtin_amdgcn_s_setprio(0);
        __builtin_amdgcn_sched_barrier(0);
        __builtin_amdgcn_s_barrier();
    }
#undef STAGEB

#pragma unroll
    for (int ft = 0; ft < 4; ++ft) {
#pragma unroll
        for (int r = 0; r < 4; ++r) {
            int t = t0 + ft * 16 + q * 4 + r;
            if (t < TGT) {
                size_t rowoff = ((size_t)(b * TGT + t)) * OCc;
#pragma unroll
                for (int fj = 0; fj < 2; ++fj) {
                    int m = wid * 32 + fj * 16 + r15;
                    Y[rowoff + m] = accB[ft][fj][r] + b2[m];
                }
            }
        }
    }
}

// ============================================================
extern "C" void kernel_launch(void* const* d_in, const int* in_sizes, int n_in,
                              void* d_out, int out_size, void* d_ws, size_t ws_size,
                              hipStream_t stream)
{
    const float* inputs   = (const float*)d_in[0];
    const float* cond     = (const float*)d_in[1];
    const float* input_w  = (const float*)d_in[2];
    const float* filter_w = (const float*)d_in[3];
    const float* gate_w   = (const float*)d_in[4];
    const float* res_w    = (const float*)d_in[5];
    const float* split_w  = (const float*)d_in[6];
    const float* gcf_w    = (const float*)d_in[7];
    const float* gcs_w    = (const float*)d_in[8];
    const float* f1_w     = (const float*)d_in[9];
    const float* f1_b     = (const float*)d_in[10];
    const float* f2_w     = (const float*)d_in[11];
    const float* f2_b     = (const float*)d_in[12];
    float* out = (float*)d_out;

    char* wsb = (char*)d_ws;
    const size_t RES_B   = (size_t)Bc * RCc * Lc * 4;
    const size_t OUTS_B  = (size_t)Bc * TGT * KTOT * 2;
    const size_t FIN_B   = (size_t)Bc * TGT * SCc * 2;
    const size_t W1_B    = (size_t)SCc * KTOT * 2;
    const size_t W2_B    = (size_t)ECc * SCc * 2;
    const size_t W3_B    = (size_t)OCc * ECc * 2;
    const size_t WFG_B   = (size_t)NL * 64 * 64 * 2;
    const size_t WR_B    = (size_t)NL * 32 * 64 * 2;

    float* res0              = (float*)wsb;                   size_t off = RES_B;
    float* res1              = (float*)(wsb + off);           off += RES_B;
    __hip_bfloat16* outsT    = (__hip_bfloat16*)(wsb + off);  off += OUTS_B;
    __hip_bfloat16* finalT   = (__hip_bfloat16*)(wsb + off);  off += FIN_B;
    __hip_bfloat16* Wp1      = (__hip_bfloat16*)(wsb + off);  off += W1_B;
    __hip_bfloat16* Wp2      = (__hip_bfloat16*)(wsb + off);  off += W2_B;
    __hip_bfloat16* Wp3      = (__hip_bfloat16*)(wsb + off);  off += W3_B;
    __hip_bfloat16* wfgp     = (__hip_bfloat16*)(wsb + off);  off += WFG_B;
    __hip_bfloat16* wrp      = (__hip_bfloat16*)(wsb + off);  off += WR_B;

    // prep: packs + input conv in one node
    {
        const int NTOT = SCc * KTOT + ECc * SCc + OCc * ECc + NL * 64 * 64;
        const int npack = (NTOT + 255) / 256;
        prep_kernel<<<npack + Bc * 128, 256, 0, stream>>>(
            inputs, input_w, res0,
            split_w, f1_w, f2_w, filter_w, gate_w, res_w,
            Wp1, Wp2, Wp3, wfgp, wrp, npack);
    }

    float* rin = res0;
    float* rout = res1;
    const dim3 lgrid(Lc / 64, Bc);
    const dim3 sgrid(128, Bc);   // 32 residues x 4 segments

    layer_group5<<<lgrid, 512, 0, stream>>>(
        rin, rout, outsT, wfgp, wrp, cond, gcf_w, gcs_w, 0);
    { float* t = rin; rin = rout; rout = t; }
    layer_groupS<false><<<sgrid, 512, 0, stream>>>(
        rin, rout, outsT, wfgp, wrp, cond, gcf_w, gcs_w, 5);
    { float* t = rin; rin = rout; rout = t; }
    layer_group5<<<lgrid, 512, 0, stream>>>(
        rin, rout, outsT, wfgp, wrp, cond, gcf_w, gcs_w, 10);
    { float* t = rin; rin = rout; rout = t; }
    layer_groupS<true><<<sgrid, 512, 0, stream>>>(
        rin, rout, outsT, wfgp, wrp, cond, gcf_w, gcs_w, 15);

    // G1: finalT = relu( outsT(12292x640) @ Wp1^T )   -> bf16 [t][1024]
    gemm_mfma64<true, 10><<<(SCc / 64) * Bc * TTILES, 256, 0, stream>>>(
        outsT, Wp1, nullptr, finalT, SCc, SCc / 64);

    // G2+G3 fused: out = (relu(finalT@Wp2^T + f1_b)) @ Wp3^T + f2_b
    gemm_fused23<<<Bc * T64, 512, 0, stream>>>(
        finalT, Wp2, f1_b, Wp3, f2_b, out);
}

// Round 19
// 156.473 us; speedup vs baseline: 1.0744x; 1.0426x over previous
//
#include <hip/hip_runtime.h>
#include <hip/hip_bf16.h>
#include <cstddef>

// ---- problem constants ----
#define Bc   2
#define Lc   8192
#define TGT  6146          // L - RF, RF = 2046
#define NL   20            // layers
#define RCc  32
#define DCc  32
#define SCc  1024
#define ECc  512
#define OCc  256
#define KTOT (NL * DCc)    // 640
#define TTILES 49          // ceil(TGT/128)
#define T64   97           // ceil(TGT/64)

typedef __attribute__((ext_vector_type(4))) float f32x4;
typedef __attribute__((ext_vector_type(8))) short bf16x8;
typedef __attribute__((ext_vector_type(4))) int i32x4;
typedef __attribute__((ext_vector_type(2))) int i32x2;

typedef __attribute__((address_space(1))) void* as1v;
typedef __attribute__((address_space(3))) void* as3v;

__device__ inline bf16x8 cvt8(const float4* p) {
    float4 a = p[0], b = p[1];
    union { bf16x8 v; __hip_bfloat16 h[8]; } u;
    u.h[0] = __float2bfloat16(a.x); u.h[1] = __float2bfloat16(a.y);
    u.h[2] = __float2bfloat16(a.z); u.h[3] = __float2bfloat16(a.w);
    u.h[4] = __float2bfloat16(b.x); u.h[5] = __float2bfloat16(b.y);
    u.h[6] = __float2bfloat16(b.z); u.h[7] = __float2bfloat16(b.w);
    return u.v;
}

// ============================================================
// prep kernel: weight packs (blocks [0,npack)) + input 1x1 conv
// ============================================================
__global__ __launch_bounds__(256) void prep_kernel(
    const float* __restrict__ x,        // [B][256][L]
    const float* __restrict__ iw,       // [32][256]
    float* __restrict__ res_out,        // [B][32][L]
    const float* __restrict__ split_w,
    const float* __restrict__ f1_w,
    const float* __restrict__ f2_w,
    const float* __restrict__ filt,
    const float* __restrict__ gate,
    const float* __restrict__ resw,
    __hip_bfloat16* __restrict__ Wp1,
    __hip_bfloat16* __restrict__ Wp2,
    __hip_bfloat16* __restrict__ Wp3,
    __hip_bfloat16* __restrict__ wfgp,
    __hip_bfloat16* __restrict__ wrp,
    int npack)
{
    __shared__ float ws[32][256];
    __shared__ float xs[64][64];
    int tid = threadIdx.x;

    if ((int)blockIdx.x < npack) {
        int idx = blockIdx.x * 256 + tid;
        const int N1 = SCc * KTOT, N2 = ECc * SCc, N3 = OCc * ECc, N4 = NL * 64 * 64;
        if (idx < N1) {
            int m = idx / KTOT, k = idx % KTOT;
            int i = k >> 5, c = k & 31;
            Wp1[idx] = __float2bfloat16(split_w[((size_t)i * SCc + m) * DCc + c]);
            return;
        }
        idx -= N1;
        if (idx < N2) { Wp2[idx] = __float2bfloat16(f1_w[idx]); return; }
        idx -= N2;
        if (idx < N3) { Wp3[idx] = __float2bfloat16(f2_w[idx]); return; }
        idx -= N3;
        if (idx < N4) {
            int li = idx / 4096, r = idx % 4096;
            int m = r >> 6, k = r & 63;
            int tap = k >> 5, ic = k & 31;
            float v = (m < 32) ? filt[(size_t)li * 2048 + (m * 32 + ic) * 2 + tap]
                               : gate[(size_t)li * 2048 + ((m - 32) * 32 + ic) * 2 + tap];
            int slot = (k >> 3) ^ (m & 7);
            wfgp[((size_t)li * 64 + m) * 64 + slot * 8 + (k & 7)] = __float2bfloat16(v);
            if (r < 2048) {
                int m2 = r >> 6;
                float v2 = (k < 32) ? resw[(size_t)li * 1024 + m2 * 32 + k] : 0.f;
                wrp[((size_t)li * 32 + m2) * 64 + slot * 8 + (k & 7)] = __float2bfloat16(v2);
            }
        }
        return;
    }

    // ---- input conv part ----
    int bid = blockIdx.x - npack;
    int b   = bid >> 7;
    int t0  = (bid & 127) * 64;

    for (int idx = tid; idx < 32 * 256; idx += 256)
        ws[idx >> 8][idx & 255] = iw[idx];

    int tl = tid & 63, qq = tid >> 6, oc0 = qq * 8;
    float acc[8] = {};

    for (int icc = 0; icc < 4; ++icc) {
        __syncthreads();
        for (int idx = tid; idx < 64 * 64; idx += 256) {
            int icl = idx >> 6, tll = idx & 63;
            xs[icl][tll] = x[((size_t)b * 256 + icc * 64 + icl) * Lc + t0 + tll];
        }
        __syncthreads();
        for (int icl = 0; icl < 64; icl += 4) {
            float x0 = xs[icl][tl], x1 = xs[icl + 1][tl];
            float x2 = xs[icl + 2][tl], x3 = xs[icl + 3][tl];
#pragma unroll
            for (int j = 0; j < 8; ++j) {
                const float4 w4 = *(const float4*)&ws[oc0 + j][icc * 64 + icl];
                acc[j] += w4.x * x0 + w4.y * x1 + w4.z * x2 + w4.w * x3;
            }
        }
    }
#pragma unroll
    for (int j = 0; j < 8; ++j)
        res_out[((size_t)b * 32 + oc0 + j) * Lc + t0 + tl] = acc[j];
}

// ============================================================
// grouped layers d=1..16 (stride-1), W=96, 512 thr.
// 1 barrier/layer: resL double-buffered (phase1 reads rc,
// phase3 writes rn); OsL cols are per-wave exclusive so
// phase1->phase3 needs no barrier (same-wave LDS ordering).
// Math bit-identical (same taps/MFMA order/rounding).
// ============================================================
__global__ __launch_bounds__(512) void layer_group5(
    const float* __restrict__ res_in,
    float* __restrict__ res_out,
    __hip_bfloat16* __restrict__ outsT,
    const __hip_bfloat16* __restrict__ wfgp,
    const __hip_bfloat16* __restrict__ wrp,
    const float* __restrict__ cond,
    const float* __restrict__ gcf_w,
    const float* __restrict__ gcs_w,
    int l0, int t0off)
{
    constexpr int W = 96, H = 32, NT = 6;
    __shared__ __align__(16) float resA[W * 36];
    __shared__ __align__(16) float resB[W * 36];
    __shared__ __align__(16) unsigned short OsL[W * 40];
    __shared__ __align__(16) i32x4 Wf[2][64 * 8];
    __shared__ __align__(16) i32x4 Wrs[2][32 * 8];

    int tid  = threadIdx.x;
    int b    = blockIdx.y;
    int t0   = (t0off + blockIdx.x) * 64;
    int lane = tid & 63, wid = tid >> 6;
    int r15  = lane & 15, q = lane >> 4;

    const float* rb = res_in + (size_t)b * 32 * Lc;
    for (int idx = tid; idx < W * 32; idx += 512) {
        int ch = idx / W, tl = idx % W;
        int tg = t0 - H + tl;
        resA[tl * 36 + ch] = (tg >= 0) ? rb[(size_t)ch * Lc + tg] : 0.f;
    }

    auto issueW = [&](int bufi, int li2) {
        const __hip_bfloat16* wfg = wfgp + (size_t)li2 * 4096;
        const __hip_bfloat16* wrl = wrp  + (size_t)li2 * 2048;
        __builtin_amdgcn_global_load_lds(
            (as1v)(void*)((const i32x4*)wfg + wid * 64 + lane),
            (as3v)(void*)&Wf[bufi][wid * 64], 16, 0, 0);
        if (wid < 4)
            __builtin_amdgcn_global_load_lds(
                (as1v)(void*)((const i32x4*)wrl + wid * 64 + lane),
                (as3v)(void*)&Wrs[bufi][wid * 64], 16, 0, 0);
    };
    issueW(0, l0);

#pragma unroll
    for (int i = 0; i < 5; ++i) {
        const int cur = i & 1;
        const float* rc = cur ? resB : resA;
        float*       rn = cur ? resA : resB;
        int li = l0 + i;
        int d  = 1 << i;

        float gf = 0.f, gg = 0.f;
#pragma unroll
        for (int c = 0; c < 5; ++c) {
            gf += gcf_w[li * 5 + c] * cond[b * 5 + c];
            gg += gcs_w[li * 5 + c] * cond[b * 5 + c];
        }
        __syncthreads();   // weights[cur] ready; prev layer rn complete
        if (i + 1 < 5) issueW(cur ^ 1, li + 1);

        if (wid < NT) {
            int ct0 = wid * 16;
            // ---- phase 1: gated conv (own 16 cols) ----
            const bf16x8* Wv = (const bf16x8*)Wf[cur];
            int srow0 = ct0 + r15 - d; if (srow0 < 0) srow0 = 0;
            int srow1 = ct0 + r15;
            bf16x8 a0 = cvt8((const float4*)&rc[srow0 * 36 + q * 8]);
            bf16x8 a1 = cvt8((const float4*)&rc[srow1 * 36 + q * 8]);
            int sg0 = q ^ (r15 & 7), sg1 = (4 + q) ^ (r15 & 7);
            f32x4 acc[4] = {};
#pragma unroll
            for (int fj = 0; fj < 4; ++fj)
                acc[fj] = __builtin_amdgcn_mfma_f32_16x16x32_bf16(
                    a0, Wv[(fj * 16 + r15) * 8 + sg0], acc[fj], 0, 0, 0);
#pragma unroll
            for (int fj = 0; fj < 4; ++fj)
                acc[fj] = __builtin_amdgcn_mfma_f32_16x16x32_bf16(
                    a1, Wv[(fj * 16 + r15) * 8 + sg1], acc[fj], 0, 0, 0);
#pragma unroll
            for (int fj = 0; fj < 2; ++fj) {
#pragma unroll
                for (int r = 0; r < 4; ++r) {
                    float F = acc[fj][r] + gf;
                    float G = acc[fj + 2][r] + gg;
                    float th  = 1.f - 2.f / (__expf(2.f * F) + 1.f);
                    float sgm = 1.f / (1.f + __expf(-G));
                    float o   = th * sgm;
                    int col = ct0 + q * 4 + r;
                    int ch  = fj * 16 + r15;
                    __hip_bfloat16 ob = __float2bfloat16(o);
                    OsL[col * 40 + ch] = *(unsigned short*)&ob;
                }
            }

            // ---- outsT write (own cols; same-wave OsL read) ----
            {
                int col = ct0 + (lane >> 2), chunk = lane & 3;
                if (col >= H) {
                    int t = t0 + col - H;
                    if (t >= Lc - TGT)
                        *(i32x4*)(outsT + ((size_t)(b * TGT + t - (Lc - TGT))) * KTOT
                                  + li * 32 + chunk * 8) =
                            *(const i32x4*)&OsL[col * 40 + chunk * 8];
                }
            }

            // ---- phase 3: residual conv; write rn (own cols) ----
            const bf16x8* Rv = (const bf16x8*)Wrs[cur];
            const bf16x8* Ov = (const bf16x8*)OsL;
            bf16x8 ao = Ov[(ct0 + r15) * 5 + q];
            int sg = q ^ (r15 & 7);
            f32x4 racc[2] = {};
#pragma unroll
            for (int fj = 0; fj < 2; ++fj)
                racc[fj] = __builtin_amdgcn_mfma_f32_16x16x32_bf16(
                    ao, Rv[(fj * 16 + r15) * 8 + sg], racc[fj], 0, 0, 0);
#pragma unroll
            for (int fj = 0; fj < 2; ++fj)
#pragma unroll
                for (int r = 0; r < 4; ++r) {
                    int col = ct0 + q * 4 + r;
                    int ch  = fj * 16 + r15;
                    float base = rc[col * 36 + ch];
                    rn[col * 36 + ch] = (t0 + col - H >= 0) ? base + racc[fj][r] : base;
                }
        }
    }
    __syncthreads();

    {   // final data in resB (after odd number of layers = 5)
        int ch = tid >> 4, t4 = (tid & 15) * 4;
        float v[4];
#pragma unroll
        for (int j = 0; j < 4; ++j) v[j] = resB[(H + t4 + j) * 36 + ch];
        float* ro = res_out + ((size_t)(b * 32) + ch) * Lc + t0 + t4;
        *(float4*)ro = make_float4(v[0], v[1], v[2], v[3]);
    }
}

// ============================================================
// strided grouped layers d=32..512 (stride-32 residues),
// same 1-barrier/dbuf structure. Bit-identical math.
// ============================================================
template <bool LASTHALF>
__global__ __launch_bounds__(512) void layer_groupS(
    const float* __restrict__ res_in,
    float* __restrict__ res_out,
    __hip_bfloat16* __restrict__ outsT,
    const __hip_bfloat16* __restrict__ wfgp,
    const __hip_bfloat16* __restrict__ wrp,
    const float* __restrict__ cond,
    const float* __restrict__ gcf_w,
    const float* __restrict__ gcs_w,
    int l0)
{
    constexpr int W = 96, H = 32, NT = 6, S = 32;
    __shared__ __align__(16) float resA[W * 36];
    __shared__ __align__(16) float resB[W * 36];
    __shared__ __align__(16) unsigned short OsL[W * 40];
    __shared__ __align__(16) i32x4 Wf[2][64 * 8];
    __shared__ __align__(16) i32x4 Wrs[2][32 * 8];

    int tid  = threadIdx.x;
    int b    = blockIdx.y;
    int r    = blockIdx.x & 31;
    int c0   = (blockIdx.x >> 5) * 64;
    int lane = tid & 63, wid = tid >> 6;
    int r15  = lane & 15, q = lane >> 4;

    const float* rb = res_in + (size_t)b * 32 * Lc;
    for (int idx = tid; idx < W * 32; idx += 512) {
        int ch = idx / W, col = idx % W;
        int cj = c0 + col - H;
        resA[col * 36 + ch] = (cj >= 0) ? rb[(size_t)ch * Lc + r + S * cj] : 0.f;
    }

    auto issueW = [&](int bufi, int li2) {
        const __hip_bfloat16* wfg = wfgp + (size_t)li2 * 4096;
        const __hip_bfloat16* wrl = wrp  + (size_t)li2 * 2048;
        __builtin_amdgcn_global_load_lds(
            (as1v)(void*)((const i32x4*)wfg + wid * 64 + lane),
            (as3v)(void*)&Wf[bufi][wid * 64], 16, 0, 0);
        if (wid < 4)
            __builtin_amdgcn_global_load_lds(
                (as1v)(void*)((const i32x4*)wrl + wid * 64 + lane),
                (as3v)(void*)&Wrs[bufi][wid * 64], 16, 0, 0);
    };
    issueW(0, l0);

#pragma unroll
    for (int i = 0; i < 5; ++i) {
        const int cur = i & 1;
        const float* rc = cur ? resB : resA;
        float*       rn = cur ? resA : resB;
        int li = l0 + i;
        int dc = 1 << i;

        float gf = 0.f, gg = 0.f;
#pragma unroll
        for (int c = 0; c < 5; ++c) {
            gf += gcf_w[li * 5 + c] * cond[b * 5 + c];
            gg += gcs_w[li * 5 + c] * cond[b * 5 + c];
        }
        __syncthreads();
        if (i + 1 < 5) issueW(cur ^ 1, li + 1);

        if (wid < NT) {
            int ct0 = wid * 16;
            const bf16x8* Wv = (const bf16x8*)Wf[cur];
            int srow0 = ct0 + r15 - dc; if (srow0 < 0) srow0 = 0;
            int srow1 = ct0 + r15;
            bf16x8 a0 = cvt8((const float4*)&rc[srow0 * 36 + q * 8]);
            bf16x8 a1 = cvt8((const float4*)&rc[srow1 * 36 + q * 8]);
            int sg0 = q ^ (r15 & 7), sg1 = (4 + q) ^ (r15 & 7);
            f32x4 acc[4] = {};
#pragma unroll
            for (int fj = 0; fj < 4; ++fj)
                acc[fj] = __builtin_amdgcn_mfma_f32_16x16x32_bf16(
                    a0, Wv[(fj * 16 + r15) * 8 + sg0], acc[fj], 0, 0, 0);
#pragma unroll
            for (int fj = 0; fj < 4; ++fj)
                acc[fj] = __builtin_amdgcn_mfma_f32_16x16x32_bf16(
                    a1, Wv[(fj * 16 + r15) * 8 + sg1], acc[fj], 0, 0, 0);
#pragma unroll
            for (int fj = 0; fj < 2; ++fj) {
#pragma unroll
                for (int rr = 0; rr < 4; ++rr) {
                    float F = acc[fj][rr] + gf;
                    float G = acc[fj + 2][rr] + gg;
                    float th  = 1.f - 2.f / (__expf(2.f * F) + 1.f);
                    float sgm = 1.f / (1.f + __expf(-G));
                    float o   = th * sgm;
                    int col = ct0 + q * 4 + rr;
                    int ch  = fj * 16 + r15;
                    __hip_bfloat16 ob = __float2bfloat16(o);
                    OsL[col * 40 + ch] = *(unsigned short*)&ob;
                }
            }

            {
                int col = ct0 + (lane >> 2), chunk = lane & 3;
                if (col >= H) {
                    int t = r + S * (c0 + col - H);
                    if (t >= Lc - TGT)
                        *(i32x4*)(outsT + ((size_t)(b * TGT + t - (Lc - TGT))) * KTOT
                                  + li * 32 + chunk * 8) =
                            *(const i32x4*)&OsL[col * 40 + chunk * 8];
                }
            }

            if (!(LASTHALF && i == 4)) {
                const bf16x8* Rv = (const bf16x8*)Wrs[cur];
                const bf16x8* Ov = (const bf16x8*)OsL;
                bf16x8 ao = Ov[(ct0 + r15) * 5 + q];
                int sg = q ^ (r15 & 7);
                f32x4 racc[2] = {};
#pragma unroll
                for (int fj = 0; fj < 2; ++fj)
                    racc[fj] = __builtin_amdgcn_mfma_f32_16x16x32_bf16(
                        ao, Rv[(fj * 16 + r15) * 8 + sg], racc[fj], 0, 0, 0);
#pragma unroll
                for (int fj = 0; fj < 2; ++fj)
#pragma unroll
                    for (int rr = 0; rr < 4; ++rr) {
                        int col = ct0 + q * 4 + rr;
                        int ch  = fj * 16 + r15;
                        float base = rc[col * 36 + ch];
                        rn[col * 36 + ch] = (c0 + col - H >= 0) ? base + racc[fj][rr] : base;
                    }
            }
        }
    }

    if (!LASTHALF) {
        __syncthreads();
        int ch = tid >> 4, t4 = (tid & 15) * 4;
#pragma unroll
        for (int j = 0; j < 4; ++j) {
            int t = r + S * (c0 + t4 + j);
            res_out[((size_t)(b * 32) + ch) * Lc + t] = resB[(H + t4 + j) * 36 + ch];
        }
    }
}

// ============================================================
// G1: bf16 MFMA GEMM, 128t x 64m tile, 48KB dbuf (unchanged R18)
// ============================================================
template <bool RELU_OUT, int NKT>
__global__ __launch_bounds__(256) void gemm_mfma64(
    const __hip_bfloat16* __restrict__ X,
    const __hip_bfloat16* __restrict__ W,
    const float* __restrict__ bias,
    __hip_bfloat16* __restrict__ Y,
    int M, int MB)   // MB = M/64
{
    constexpr int K = NKT * 64;
    __shared__ __align__(16) char smem[49152];
    i32x4* Xs0 = (i32x4*)smem;
    i32x4* Ws0 = (i32x4*)(smem + 16384);
    i32x4* Xs1 = (i32x4*)(smem + 24576);
    i32x4* Ws1 = (i32x4*)(smem + 40960);

    int nwg  = gridDim.x;
    int orig = blockIdx.x;
    int q8 = nwg >> 3, r8 = nwg & 7;
    int xcd = orig & 7, loc = orig >> 3;
    int wgid = (xcd < r8 ? xcd * (q8 + 1) : r8 * (q8 + 1) + (xcd - r8) * q8) + loc;
    int mi  = wgid % MB;
    int byy = wgid / MB;
    int b   = byy / TTILES;
    int t0  = (byy % TTILES) * 128;
    int m0  = mi * 64;

    int tid = threadIdx.x;
    int lane = tid & 63, wid = tid >> 6;
    int r15 = lane & 15, q = lane >> 4;

    int subrow = lane >> 3;
    int g      = (lane & 7) ^ subrow;
    const __hip_bfloat16* xp[4];
    const __hip_bfloat16* wp[2];
#pragma unroll
    for (int i = 0; i < 4; ++i) {
        int r = wid * 32 + i * 8 + subrow;
        int xrow = t0 + r; if (xrow > TGT - 1) xrow = TGT - 1;
        xp[i] = X + ((size_t)(b * TGT + xrow)) * K + g * 8;
    }
#pragma unroll
    for (int i = 0; i < 2; ++i) {
        int r = wid * 16 + i * 8 + subrow;
        wp[i] = W + ((size_t)(m0 + r)) * K + g * 8;
    }

    f32x4 acc[2][4] = {};

#define STAGE(XB, WB)                                                          \
    {                                                                          \
        _Pragma("unroll")                                                      \
        for (int i = 0; i < 4; ++i) {                                          \
            __builtin_amdgcn_global_load_lds((as1v)(void*)xp[i],               \
                (as3v)(void*)&XB[(wid * 4 + i) * 64], 16, 0, 0);               \
            xp[i] += 64;                                                       \
        }                                                                      \
        _Pragma("unroll")                                                      \
        for (int i = 0; i < 2; ++i) {                                          \
            __builtin_amdgcn_global_load_lds((as1v)(void*)wp[i],               \
                (as3v)(void*)&WB[(wid * 2 + i) * 64], 16, 0, 0);               \
            wp[i] += 64;                                                       \
        }                                                                      \
    }

    auto compute = [&](const i32x4* Xb, const i32x4* Wb) {
        const bf16x8* Xv = (const bf16x8*)Xb;
        const bf16x8* Wv = (const bf16x8*)Wb;
#pragma unroll
        for (int kk = 0; kk < 2; ++kk) {
            int sg = (kk * 4 + q) ^ (r15 & 7);
            bf16x8 af[2], bw[4];
#pragma unroll
            for (int ft = 0; ft < 2; ++ft)
                af[ft] = Xv[(wid * 32 + ft * 16 + r15) * 8 + sg];
#pragma unroll
            for (int fj = 0; fj < 4; ++fj)
                bw[fj] = Wv[(fj * 16 + r15) * 8 + sg];
#pragma unroll
            for (int ft = 0; ft < 2; ++ft)
#pragma unroll
                for (int fj = 0; fj < 4; ++fj)
                    acc[ft][fj] = __builtin_amdgcn_mfma_f32_16x16x32_bf16(
                        af[ft], bw[fj], acc[ft][fj], 0, 0, 0);
        }
    };

    STAGE(Xs0, Ws0);

#pragma unroll
    for (int kt2 = 0; kt2 < NKT; kt2 += 2) {
        STAGE(Xs1, Ws1);
        asm volatile("s_waitcnt vmcnt(6)" ::: "memory");
        __builtin_amdgcn_s_barrier();
        __builtin_amdgcn_sched_barrier(0);
        __builtin_amdgcn_s_setprio(1);
        compute(Xs0, Ws0);
        __builtin_amdgcn_s_setprio(0);
        __builtin_amdgcn_sched_barrier(0);
        __builtin_amdgcn_s_barrier();

        if (kt2 + 2 < NKT) {
            STAGE(Xs0, Ws0);
            asm volatile("s_waitcnt vmcnt(6)" ::: "memory");
        } else {
            asm volatile("s_waitcnt vmcnt(0)" ::: "memory");
        }
        __builtin_amdgcn_s_barrier();
        __builtin_amdgcn_sched_barrier(0);
        __builtin_amdgcn_s_setprio(1);
        compute(Xs1, Ws1);
        __builtin_amdgcn_s_setprio(0);
        __builtin_amdgcn_sched_barrier(0);
        __builtin_amdgcn_s_barrier();
    }
#undef STAGE

    __hip_bfloat16* Eb = (__hip_bfloat16*)smem;   // [128][72] padded
#pragma unroll
    for (int ft = 0; ft < 2; ++ft) {
#pragma unroll
        for (int r = 0; r < 4; ++r) {
            int tl = wid * 32 + ft * 16 + q * 4 + r;
#pragma unroll
            for (int fj = 0; fj < 4; ++fj) {
                int ml = fj * 16 + r15;
                float v = acc[ft][fj][r];
                if (bias) v += bias[m0 + ml];
                if (RELU_OUT) v = fmaxf(v, 0.f);
                Eb[tl * 72 + ml] = __float2bfloat16(v);
            }
        }
    }
    __syncthreads();
    {
        int row = tid >> 1, half = tid & 1;
        int t = t0 + row;
        if (t < TGT) {
            __hip_bfloat16* dst = Y + ((size_t)(b * TGT + t)) * M + m0 + half * 32;
            const __hip_bfloat16* src = Eb + row * 72 + half * 32;
#pragma unroll
            for (int k = 0; k < 4; ++k)
                ((i32x4*)dst)[k] = ((const i32x4*)src)[k];
        }
    }
}

// ============================================================
// FUSED G2+G3 (unchanged from R16)
// ============================================================
__global__ __launch_bounds__(512) void gemm_fused23(
    const __hip_bfloat16* __restrict__ X,    // finalT [B*TGT][1024]
    const __hip_bfloat16* __restrict__ W2,   // [512][1024]
    const float* __restrict__ b1,            // [512]
    const __hip_bfloat16* __restrict__ W3,   // [256][512]
    const float* __restrict__ b2,            // [256]
    float* __restrict__ Y)                   // [B*TGT][256]
{
    __shared__ __align__(16) char smem[153600];
    i32x4* Xs[2] = { (i32x4*)smem, (i32x4*)(smem + 8192) };
    i32x4* Ws[2] = { (i32x4*)(smem + 16384), (i32x4*)(smem + 81920) };
    __hip_bfloat16* Hs = (__hip_bfloat16*)(smem + 16384);
    i32x4* W3s[2] = { (i32x4*)(smem + 88064), (i32x4*)(smem + 120832) };

    int nwg  = gridDim.x;
    int orig = blockIdx.x;
    int q8 = nwg >> 3, r8 = nwg & 7;
    int xcd = orig & 7, loc = orig >> 3;
    int wgid = (xcd < r8 ? xcd * (q8 + 1) : r8 * (q8 + 1) + (xcd - r8) * q8) + loc;
    int b  = wgid / T64;
    int t0 = (wgid % T64) * 64;

    int tid = threadIdx.x;
    int lane = tid & 63, wid = tid >> 6;
    int r15 = lane & 15, q = lane >> 4;
    int subrow = lane >> 3;
    int g      = (lane & 7) ^ subrow;

    int xr = wid * 8 + subrow;
    int xrow = t0 + xr; if (xrow > TGT - 1) xrow = TGT - 1;
    const __hip_bfloat16* xp = X + ((size_t)(b * TGT + xrow)) * SCc + g * 8;
    const __hip_bfloat16* wp[8];
#pragma unroll
    for (int i = 0; i < 8; ++i)
        wp[i] = W2 + ((size_t)((wid * 8 + i) * 8 + subrow)) * SCc + g * 8;

    f32x4 acc[4][4] = {};

#define STAGEA(bi)                                                             \
    {                                                                          \
        __builtin_amdgcn_global_load_lds((as1v)(void*)xp,                      \
            (as3v)(void*)&Xs[bi][wid * 64], 16, 0, 0);                         \
        xp += 64;                                                              \
        _Pragma("unroll")                                                      \
        for (int i = 0; i < 8; ++i) {                                          \
            __builtin_amdgcn_global_load_lds((as1v)(void*)wp[i],               \
                (as3v)(void*)&Ws[bi][(wid * 8 + i) * 64], 16, 0, 0);           \
            wp[i] += 64;                                                       \
        }                                                                      \
    }

    auto computeA = [&](const i32x4* Xb, const i32x4* Wb) {
        const bf16x8* Xv = (const bf16x8*)Xb;
        const bf16x8* Wv = (const bf16x8*)Wb;
#pragma unroll
        for (int kk = 0; kk < 2; ++kk) {
            int sg = (kk * 4 + q) ^ (r15 & 7);
            bf16x8 af[4], bw[4];
#pragma unroll
            for (int ft = 0; ft < 4; ++ft)
                af[ft] = Xv[(ft * 16 + r15) * 8 + sg];
#pragma unroll
            for (int fj = 0; fj < 4; ++fj)
                bw[fj] = Wv[(wid * 64 + fj * 16 + r15) * 8 + sg];
#pragma unroll
            for (int ft = 0; ft < 4; ++ft)
#pragma unroll
                for (int fj = 0; fj < 4; ++fj)
                    acc[ft][fj] = __builtin_amdgcn_mfma_f32_16x16x32_bf16(
                        af[ft], bw[fj], acc[ft][fj], 0, 0, 0);
        }
    };

    STAGEA(0);
#pragma unroll
    for (int kt = 0; kt < 16; ++kt) {
        const int cur = kt & 1;
        if (kt + 1 < 16) {
            STAGEA(cur ^ 1);
            asm volatile("s_waitcnt vmcnt(9)" ::: "memory");
        } else {
            asm volatile("s_waitcnt vmcnt(0)" ::: "memory");
        }
        __builtin_amdgcn_s_barrier();
        __builtin_amdgcn_sched_barrier(0);
        __builtin_amdgcn_s_setprio(1);
        computeA(Xs[cur], Ws[cur]);
        __builtin_amdgcn_s_setprio(0);
        __builtin_amdgcn_sched_barrier(0);
        __builtin_amdgcn_s_barrier();
    }
#undef STAGEA

#pragma unroll
    for (int ft = 0; ft < 4; ++ft) {
#pragma unroll
        for (int r = 0; r < 4; ++r) {
            int tl = ft * 16 + q * 4 + r;
#pragma unroll
            for (int fj = 0; fj < 4; ++fj) {
                int m = wid * 64 + fj * 16 + r15;
                float v = acc[ft][fj][r] + b1[m];
                v = fmaxf(v, 0.f);
                Hs[tl * 520 + m] = __float2bfloat16(v);
            }
        }
    }

    const __hip_bfloat16* w3p[4];
#pragma unroll
    for (int i = 0; i < 4; ++i)
        w3p[i] = W3 + ((size_t)((wid * 4 + i) * 8 + subrow)) * ECc + g * 8;

#define STAGEB(bi)                                                             \
    {                                                                          \
        _Pragma("unroll")                                                      \
        for (int i = 0; i < 4; ++i) {                                          \
            __builtin_amdgcn_global_load_lds((as1v)(void*)w3p[i],              \
                (as3v)(void*)&W3s[bi][(wid * 4 + i) * 64], 16, 0, 0);          \
            w3p[i] += 64;                                                      \
        }                                                                      \
    }

    STAGEB(0);
    __syncthreads();

    f32x4 accB[4][2] = {};

#pragma unroll
    for (int kt = 0; kt < 8; ++kt) {
        const int cur = kt & 1;
        if (kt + 1 < 8) {
            STAGEB(cur ^ 1);
            asm volatile("s_waitcnt vmcnt(4)" ::: "memory");
        } else {
            asm volatile("s_waitcnt vmcnt(0)" ::: "memory");
        }
        __builtin_amdgcn_s_barrier();
        __builtin_amdgcn_sched_barrier(0);
        __builtin_amdgcn_s_setprio(1);
        {
            const bf16x8* Wv = (const bf16x8*)W3s[cur];
#pragma unroll
            for (int kk = 0; kk < 2; ++kk) {
                int gk = kt * 8 + kk * 4 + q;
                int sg = (kk * 4 + q) ^ (r15 & 7);
                bf16x8 af[4], bw[2];
#pragma unroll
                for (int ft = 0; ft < 4; ++ft)
                    af[ft] = *(const bf16x8*)&Hs[(ft * 16 + r15) * 520 + gk * 8];
#pragma unroll
                for (int fj = 0; fj < 2; ++fj)
                    bw[fj] = Wv[(wid * 32 + fj * 16 + r15) * 8 + sg];
#pragma unroll
                for (int ft = 0; ft < 4; ++ft)
#pragma unroll
                    for (int fj = 0; fj < 2; ++fj)
                        accB[ft][fj] = __builtin_amdgcn_mfma_f32_16x16x32_bf16(
                            af[ft], bw[fj], accB[ft][fj], 0, 0, 0);
            }
        }
        __builtin_amdgcn_s_setprio(0);
        __builtin_amdgcn_sched_barrier(0);
        __builtin_amdgcn_s_barrier();
    }
#undef STAGEB

#pragma unroll
    for (int ft = 0; ft < 4; ++ft) {
#pragma unroll
        for (int r = 0; r < 4; ++r) {
            int t = t0 + ft * 16 + q * 4 + r;
            if (t < TGT) {
                size_t rowoff = ((size_t)(b * TGT + t)) * OCc;
#pragma unroll
                for (int fj = 0; fj < 2; ++fj) {
                    int m = wid * 32 + fj * 16 + r15;
                    Y[rowoff + m] = accB[ft][fj][r] + b2[m];
                }
            }
        }
    }
}

// ============================================================
extern "C" void kernel_launch(void* const* d_in, const int* in_sizes, int n_in,
                              void* d_out, int out_size, void* d_ws, size_t ws_size,
                              hipStream_t stream)
{
    const float* inputs   = (const float*)d_in[0];
    const float* cond     = (const float*)d_in[1];
    const float* input_w  = (const float*)d_in[2];
    const float* filter_w = (const float*)d_in[3];
    const float* gate_w   = (const float*)d_in[4];
    const float* res_w    = (const float*)d_in[5];
    const float* split_w  = (const float*)d_in[6];
    const float* gcf_w    = (const float*)d_in[7];
    const float* gcs_w    = (const float*)d_in[8];
    const float* f1_w     = (const float*)d_in[9];
    const float* f1_b     = (const float*)d_in[10];
    const float* f2_w     = (const float*)d_in[11];
    const float* f2_b     = (const float*)d_in[12];
    float* out = (float*)d_out;

    char* wsb = (char*)d_ws;
    const size_t RES_B   = (size_t)Bc * RCc * Lc * 4;
    const size_t OUTS_B  = (size_t)Bc * TGT * KTOT * 2;
    const size_t FIN_B   = (size_t)Bc * TGT * SCc * 2;
    const size_t W1_B    = (size_t)SCc * KTOT * 2;
    const size_t W2_B    = (size_t)ECc * SCc * 2;
    const size_t W3_B    = (size_t)OCc * ECc * 2;
    const size_t WFG_B   = (size_t)NL * 64 * 64 * 2;
    const size_t WR_B    = (size_t)NL * 32 * 64 * 2;

    float* res0              = (float*)wsb;                   size_t off = RES_B;
    float* res1              = (float*)(wsb + off);           off += RES_B;
    __hip_bfloat16* outsT    = (__hip_bfloat16*)(wsb + off);  off += OUTS_B;
    __hip_bfloat16* finalT   = (__hip_bfloat16*)(wsb + off);  off += FIN_B;
    __hip_bfloat16* Wp1      = (__hip_bfloat16*)(wsb + off);  off += W1_B;
    __hip_bfloat16* Wp2      = (__hip_bfloat16*)(wsb + off);  off += W2_B;
    __hip_bfloat16* Wp3      = (__hip_bfloat16*)(wsb + off);  off += W3_B;
    __hip_bfloat16* wfgp     = (__hip_bfloat16*)(wsb + off);  off += WFG_B;
    __hip_bfloat16* wrp      = (__hip_bfloat16*)(wsb + off);  off += WR_B;

    // prep: packs + input conv in one node
    {
        const int NTOT = SCc * KTOT + ECc * SCc + OCc * ECc + NL * 64 * 64;
        const int npack = (NTOT + 255) / 256;
        prep_kernel<<<npack + Bc * 128, 256, 0, stream>>>(
            inputs, input_w, res0,
            split_w, f1_w, f2_w, filter_w, gate_w, res_w,
            Wp1, Wp2, Wp3, wfgp, wrp, npack);
    }

    float* rin = res0;
    float* rout = res1;
    const dim3 sgrid(128, Bc);   // 32 residues x 4 segments

    // half 0
    layer_group5<<<dim3(128, Bc), 512, 0, stream>>>(
        rin, rout, outsT, wfgp, wrp, cond, gcf_w, gcs_w, 0, 0);
    { float* t = rin; rin = rout; rout = t; }
    layer_groupS<false><<<sgrid, 512, 0, stream>>>(
        rin, rout, outsT, wfgp, wrp, cond, gcf_w, gcs_w, 5);
    { float* t = rin; rin = rout; rout = t; }
    // half 1: only tiles t0 >= 960 are live downstream (RF analysis)
    layer_group5<<<dim3(113, Bc), 512, 0, stream>>>(
        rin, rout, outsT, wfgp, wrp, cond, gcf_w, gcs_w, 10, 15);
    { float* t = rin; rin = rout; rout = t; }
    layer_groupS<true><<<sgrid, 512, 0, stream>>>(
        rin, rout, outsT, wfgp, wrp, cond, gcf_w, gcs_w, 15);

    // G1: finalT = relu( outsT(12292x640) @ Wp1^T )   -> bf16 [t][1024]
    gemm_mfma64<true, 10><<<(SCc / 64) * Bc * TTILES, 256, 0, stream>>>(
        outsT, Wp1, nullptr, finalT, SCc, SCc / 64);

    // G2+G3 fused: out = (relu(finalT@Wp2^T + f1_b)) @ Wp3^T + f2_b
    gemm_fused23<<<Bc * T64, 512, 0, stream>>>(
        finalT, Wp2, f1_b, Wp3, f2_b, out);
}

// Round 20
// 156.196 us; speedup vs baseline: 1.0763x; 1.0018x over previous
//
#include <hip/hip_runtime.h>
#include <hip/hip_bf16.h>
#include <cstddef>

// ---- problem constants ----
#define Bc   2
#define Lc   8192
#define TGT  6146          // L - RF, RF = 2046
#define NL   20            // layers
#define RCc  32
#define DCc  32
#define SCc  1024
#define ECc  512
#define OCc  256
#define KTOT (NL * DCc)    // 640
#define TTILES 49          // ceil(TGT/128)
#define T64   97           // ceil(TGT/64)

typedef __attribute__((ext_vector_type(4))) float f32x4;
typedef __attribute__((ext_vector_type(8))) short bf16x8;
typedef __attribute__((ext_vector_type(4))) int i32x4;
typedef __attribute__((ext_vector_type(2))) int i32x2;

typedef __attribute__((address_space(1))) void* as1v;
typedef __attribute__((address_space(3))) void* as3v;

__device__ inline bf16x8 cvt8(const float4* p) {
    float4 a = p[0], b = p[1];
    union { bf16x8 v; __hip_bfloat16 h[8]; } u;
    u.h[0] = __float2bfloat16(a.x); u.h[1] = __float2bfloat16(a.y);
    u.h[2] = __float2bfloat16(a.z); u.h[3] = __float2bfloat16(a.w);
    u.h[4] = __float2bfloat16(b.x); u.h[5] = __float2bfloat16(b.y);
    u.h[6] = __float2bfloat16(b.z); u.h[7] = __float2bfloat16(b.w);
    return u.v;
}

// ============================================================
// prep kernel: weight packs (blocks [0,npack)) + input 1x1 conv
// ============================================================
__global__ __launch_bounds__(256) void prep_kernel(
    const float* __restrict__ x,        // [B][256][L]
    const float* __restrict__ iw,       // [32][256]
    float* __restrict__ res_out,        // [B][32][L]
    const float* __restrict__ split_w,
    const float* __restrict__ f1_w,
    const float* __restrict__ f2_w,
    const float* __restrict__ filt,
    const float* __restrict__ gate,
    const float* __restrict__ resw,
    __hip_bfloat16* __restrict__ Wp1,
    __hip_bfloat16* __restrict__ Wp2,
    __hip_bfloat16* __restrict__ Wp3,
    __hip_bfloat16* __restrict__ wfgp,
    __hip_bfloat16* __restrict__ wrp,
    int npack)
{
    __shared__ float ws[32][256];
    __shared__ float xs[64][64];
    int tid = threadIdx.x;

    if ((int)blockIdx.x < npack) {
        int idx = blockIdx.x * 256 + tid;
        const int N1 = SCc * KTOT, N2 = ECc * SCc, N3 = OCc * ECc, N4 = NL * 64 * 64;
        if (idx < N1) {
            int m = idx / KTOT, k = idx % KTOT;
            int i = k >> 5, c = k & 31;
            Wp1[idx] = __float2bfloat16(split_w[((size_t)i * SCc + m) * DCc + c]);
            return;
        }
        idx -= N1;
        if (idx < N2) { Wp2[idx] = __float2bfloat16(f1_w[idx]); return; }
        idx -= N2;
        if (idx < N3) { Wp3[idx] = __float2bfloat16(f2_w[idx]); return; }
        idx -= N3;
        if (idx < N4) {
            int li = idx / 4096, r = idx % 4096;
            int m = r >> 6, k = r & 63;
            int tap = k >> 5, ic = k & 31;
            float v = (m < 32) ? filt[(size_t)li * 2048 + (m * 32 + ic) * 2 + tap]
                               : gate[(size_t)li * 2048 + ((m - 32) * 32 + ic) * 2 + tap];
            int slot = (k >> 3) ^ (m & 7);
            wfgp[((size_t)li * 64 + m) * 64 + slot * 8 + (k & 7)] = __float2bfloat16(v);
            if (r < 2048) {
                int m2 = r >> 6;
                float v2 = (k < 32) ? resw[(size_t)li * 1024 + m2 * 32 + k] : 0.f;
                wrp[((size_t)li * 32 + m2) * 64 + slot * 8 + (k & 7)] = __float2bfloat16(v2);
            }
        }
        return;
    }

    // ---- input conv part ----
    int bid = blockIdx.x - npack;
    int b   = bid >> 7;
    int t0  = (bid & 127) * 64;

    for (int idx = tid; idx < 32 * 256; idx += 256)
        ws[idx >> 8][idx & 255] = iw[idx];

    int tl = tid & 63, qq = tid >> 6, oc0 = qq * 8;
    float acc[8] = {};

    for (int icc = 0; icc < 4; ++icc) {
        __syncthreads();
        for (int idx = tid; idx < 64 * 64; idx += 256) {
            int icl = idx >> 6, tll = idx & 63;
            xs[icl][tll] = x[((size_t)b * 256 + icc * 64 + icl) * Lc + t0 + tll];
        }
        __syncthreads();
        for (int icl = 0; icl < 64; icl += 4) {
            float x0 = xs[icl][tl], x1 = xs[icl + 1][tl];
            float x2 = xs[icl + 2][tl], x3 = xs[icl + 3][tl];
#pragma unroll
            for (int j = 0; j < 8; ++j) {
                const float4 w4 = *(const float4*)&ws[oc0 + j][icc * 64 + icl];
                acc[j] += w4.x * x0 + w4.y * x1 + w4.z * x2 + w4.w * x3;
            }
        }
    }
#pragma unroll
    for (int j = 0; j < 8; ++j)
        res_out[((size_t)b * 32 + oc0 + j) * Lc + t0 + tl] = acc[j];
}

// ============================================================
// grouped layers d=1..16 (stride-1), W=96, 512 thr.
// 1 barrier/layer: resL double-buffered (phase1 reads rc,
// phase3 writes rn); OsL cols are per-wave exclusive so
// phase1->phase3 needs no barrier (same-wave LDS ordering).
// Math bit-identical (same taps/MFMA order/rounding).
// ============================================================
__global__ __launch_bounds__(512) void layer_group5(
    const float* __restrict__ res_in,
    float* __restrict__ res_out,
    __hip_bfloat16* __restrict__ outsT,
    const __hip_bfloat16* __restrict__ wfgp,
    const __hip_bfloat16* __restrict__ wrp,
    const float* __restrict__ cond,
    const float* __restrict__ gcf_w,
    const float* __restrict__ gcs_w,
    int l0, int t0off)
{
    constexpr int W = 96, H = 32, NT = 6;
    __shared__ __align__(16) float resA[W * 36];
    __shared__ __align__(16) float resB[W * 36];
    __shared__ __align__(16) unsigned short OsL[W * 40];
    __shared__ __align__(16) i32x4 Wf[2][64 * 8];
    __shared__ __align__(16) i32x4 Wrs[2][32 * 8];

    int tid  = threadIdx.x;
    int b    = blockIdx.y;
    int t0   = (t0off + blockIdx.x) * 64;
    int lane = tid & 63, wid = tid >> 6;
    int r15  = lane & 15, q = lane >> 4;

    const float* rb = res_in + (size_t)b * 32 * Lc;
    for (int idx = tid; idx < W * 32; idx += 512) {
        int ch = idx / W, tl = idx % W;
        int tg = t0 - H + tl;
        resA[tl * 36 + ch] = (tg >= 0) ? rb[(size_t)ch * Lc + tg] : 0.f;
    }

    auto issueW = [&](int bufi, int li2) {
        const __hip_bfloat16* wfg = wfgp + (size_t)li2 * 4096;
        const __hip_bfloat16* wrl = wrp  + (size_t)li2 * 2048;
        __builtin_amdgcn_global_load_lds(
            (as1v)(void*)((const i32x4*)wfg + wid * 64 + lane),
            (as3v)(void*)&Wf[bufi][wid * 64], 16, 0, 0);
        if (wid < 4)
            __builtin_amdgcn_global_load_lds(
                (as1v)(void*)((const i32x4*)wrl + wid * 64 + lane),
                (as3v)(void*)&Wrs[bufi][wid * 64], 16, 0, 0);
    };
    issueW(0, l0);

#pragma unroll
    for (int i = 0; i < 5; ++i) {
        const int cur = i & 1;
        const float* rc = cur ? resB : resA;
        float*       rn = cur ? resA : resB;
        int li = l0 + i;
        int d  = 1 << i;

        float gf = 0.f, gg = 0.f;
#pragma unroll
        for (int c = 0; c < 5; ++c) {
            gf += gcf_w[li * 5 + c] * cond[b * 5 + c];
            gg += gcs_w[li * 5 + c] * cond[b * 5 + c];
        }
        __syncthreads();   // weights[cur] ready; prev layer rn complete
        if (i + 1 < 5) issueW(cur ^ 1, li + 1);

        if (wid < NT) {
            int ct0 = wid * 16;
            // ---- phase 1: gated conv (own 16 cols) ----
            const bf16x8* Wv = (const bf16x8*)Wf[cur];
            int srow0 = ct0 + r15 - d; if (srow0 < 0) srow0 = 0;
            int srow1 = ct0 + r15;
            bf16x8 a0 = cvt8((const float4*)&rc[srow0 * 36 + q * 8]);
            bf16x8 a1 = cvt8((const float4*)&rc[srow1 * 36 + q * 8]);
            int sg0 = q ^ (r15 & 7), sg1 = (4 + q) ^ (r15 & 7);
            f32x4 acc[4] = {};
#pragma unroll
            for (int fj = 0; fj < 4; ++fj)
                acc[fj] = __builtin_amdgcn_mfma_f32_16x16x32_bf16(
                    a0, Wv[(fj * 16 + r15) * 8 + sg0], acc[fj], 0, 0, 0);
#pragma unroll
            for (int fj = 0; fj < 4; ++fj)
                acc[fj] = __builtin_amdgcn_mfma_f32_16x16x32_bf16(
                    a1, Wv[(fj * 16 + r15) * 8 + sg1], acc[fj], 0, 0, 0);
#pragma unroll
            for (int fj = 0; fj < 2; ++fj) {
#pragma unroll
                for (int r = 0; r < 4; ++r) {
                    float F = acc[fj][r] + gf;
                    float G = acc[fj + 2][r] + gg;
                    float th  = 1.f - 2.f / (__expf(2.f * F) + 1.f);
                    float sgm = 1.f / (1.f + __expf(-G));
                    float o   = th * sgm;
                    int col = ct0 + q * 4 + r;
                    int ch  = fj * 16 + r15;
                    __hip_bfloat16 ob = __float2bfloat16(o);
                    OsL[col * 40 + ch] = *(unsigned short*)&ob;
                }
            }

            // ---- outsT write (own cols; same-wave OsL read) ----
            {
                int col = ct0 + (lane >> 2), chunk = lane & 3;
                if (col >= H) {
                    int t = t0 + col - H;
                    if (t >= Lc - TGT)
                        *(i32x4*)(outsT + ((size_t)(b * TGT + t - (Lc - TGT))) * KTOT
                                  + li * 32 + chunk * 8) =
                            *(const i32x4*)&OsL[col * 40 + chunk * 8];
                }
            }

            // ---- phase 3: residual conv; write rn (own cols) ----
            const bf16x8* Rv = (const bf16x8*)Wrs[cur];
            const bf16x8* Ov = (const bf16x8*)OsL;
            bf16x8 ao = Ov[(ct0 + r15) * 5 + q];
            int sg = q ^ (r15 & 7);
            f32x4 racc[2] = {};
#pragma unroll
            for (int fj = 0; fj < 2; ++fj)
                racc[fj] = __builtin_amdgcn_mfma_f32_16x16x32_bf16(
                    ao, Rv[(fj * 16 + r15) * 8 + sg], racc[fj], 0, 0, 0);
#pragma unroll
            for (int fj = 0; fj < 2; ++fj)
#pragma unroll
                for (int r = 0; r < 4; ++r) {
                    int col = ct0 + q * 4 + r;
                    int ch  = fj * 16 + r15;
                    float base = rc[col * 36 + ch];
                    rn[col * 36 + ch] = (t0 + col - H >= 0) ? base + racc[fj][r] : base;
                }
        }
    }
    __syncthreads();

    {   // final data in resB (after odd number of layers = 5)
        int ch = tid >> 4, t4 = (tid & 15) * 4;
        float v[4];
#pragma unroll
        for (int j = 0; j < 4; ++j) v[j] = resB[(H + t4 + j) * 36 + ch];
        float* ro = res_out + ((size_t)(b * 32) + ch) * Lc + t0 + t4;
        *(float4*)ro = make_float4(v[0], v[1], v[2], v[3]);
    }
}

// ============================================================
// strided grouped layers d=32..512 (stride-32 residues),
// same 1-barrier/dbuf structure. Bit-identical math.
// ============================================================
template <bool LASTHALF>
__global__ __launch_bounds__(512) void layer_groupS(
    const float* __restrict__ res_in,
    float* __restrict__ res_out,
    __hip_bfloat16* __restrict__ outsT,
    const __hip_bfloat16* __restrict__ wfgp,
    const __hip_bfloat16* __restrict__ wrp,
    const float* __restrict__ cond,
    const float* __restrict__ gcf_w,
    const float* __restrict__ gcs_w,
    int l0)
{
    constexpr int W = 96, H = 32, NT = 6, S = 32;
    __shared__ __align__(16) float resA[W * 36];
    __shared__ __align__(16) float resB[W * 36];
    __shared__ __align__(16) unsigned short OsL[W * 40];
    __shared__ __align__(16) i32x4 Wf[2][64 * 8];
    __shared__ __align__(16) i32x4 Wrs[2][32 * 8];

    int tid  = threadIdx.x;
    int b    = blockIdx.y;
    int r    = blockIdx.x & 31;
    int c0   = (blockIdx.x >> 5) * 64;
    int lane = tid & 63, wid = tid >> 6;
    int r15  = lane & 15, q = lane >> 4;

    const float* rb = res_in + (size_t)b * 32 * Lc;
    for (int idx = tid; idx < W * 32; idx += 512) {
        int ch = idx / W, col = idx % W;
        int cj = c0 + col - H;
        resA[col * 36 + ch] = (cj >= 0) ? rb[(size_t)ch * Lc + r + S * cj] : 0.f;
    }

    auto issueW = [&](int bufi, int li2) {
        const __hip_bfloat16* wfg = wfgp + (size_t)li2 * 4096;
        const __hip_bfloat16* wrl = wrp  + (size_t)li2 * 2048;
        __builtin_amdgcn_global_load_lds(
            (as1v)(void*)((const i32x4*)wfg + wid * 64 + lane),
            (as3v)(void*)&Wf[bufi][wid * 64], 16, 0, 0);
        if (wid < 4)
            __builtin_amdgcn_global_load_lds(
                (as1v)(void*)((const i32x4*)wrl + wid * 64 + lane),
                (as3v)(void*)&Wrs[bufi][wid * 64], 16, 0, 0);
    };
    issueW(0, l0);

#pragma unroll
    for (int i = 0; i < 5; ++i) {
        const int cur = i & 1;
        const float* rc = cur ? resB : resA;
        float*       rn = cur ? resA : resB;
        int li = l0 + i;
        int dc = 1 << i;

        float gf = 0.f, gg = 0.f;
#pragma unroll
        for (int c = 0; c < 5; ++c) {
            gf += gcf_w[li * 5 + c] * cond[b * 5 + c];
            gg += gcs_w[li * 5 + c] * cond[b * 5 + c];
        }
        __syncthreads();
        if (i + 1 < 5) issueW(cur ^ 1, li + 1);

        if (wid < NT) {
            int ct0 = wid * 16;
            const bf16x8* Wv = (const bf16x8*)Wf[cur];
            int srow0 = ct0 + r15 - dc; if (srow0 < 0) srow0 = 0;
            int srow1 = ct0 + r15;
            bf16x8 a0 = cvt8((const float4*)&rc[srow0 * 36 + q * 8]);
            bf16x8 a1 = cvt8((const float4*)&rc[srow1 * 36 + q * 8]);
            int sg0 = q ^ (r15 & 7), sg1 = (4 + q) ^ (r15 & 7);
            f32x4 acc[4] = {};
#pragma unroll
            for (int fj = 0; fj < 4; ++fj)
                acc[fj] = __builtin_amdgcn_mfma_f32_16x16x32_bf16(
                    a0, Wv[(fj * 16 + r15) * 8 + sg0], acc[fj], 0, 0, 0);
#pragma unroll
            for (int fj = 0; fj < 4; ++fj)
                acc[fj] = __builtin_amdgcn_mfma_f32_16x16x32_bf16(
                    a1, Wv[(fj * 16 + r15) * 8 + sg1], acc[fj], 0, 0, 0);
#pragma unroll
            for (int fj = 0; fj < 2; ++fj) {
#pragma unroll
                for (int rr = 0; rr < 4; ++rr) {
                    float F = acc[fj][rr] + gf;
                    float G = acc[fj + 2][rr] + gg;
                    float th  = 1.f - 2.f / (__expf(2.f * F) + 1.f);
                    float sgm = 1.f / (1.f + __expf(-G));
                    float o   = th * sgm;
                    int col = ct0 + q * 4 + rr;
                    int ch  = fj * 16 + r15;
                    __hip_bfloat16 ob = __float2bfloat16(o);
                    OsL[col * 40 + ch] = *(unsigned short*)&ob;
                }
            }

            {
                int col = ct0 + (lane >> 2), chunk = lane & 3;
                if (col >= H) {
                    int t = r + S * (c0 + col - H);
                    if (t >= Lc - TGT)
                        *(i32x4*)(outsT + ((size_t)(b * TGT + t - (Lc - TGT))) * KTOT
                                  + li * 32 + chunk * 8) =
                            *(const i32x4*)&OsL[col * 40 + chunk * 8];
                }
            }

            if (!(LASTHALF && i == 4)) {
                const bf16x8* Rv = (const bf16x8*)Wrs[cur];
                const bf16x8* Ov = (const bf16x8*)OsL;
                bf16x8 ao = Ov[(ct0 + r15) * 5 + q];
                int sg = q ^ (r15 & 7);
                f32x4 racc[2] = {};
#pragma unroll
                for (int fj = 0; fj < 2; ++fj)
                    racc[fj] = __builtin_amdgcn_mfma_f32_16x16x32_bf16(
                        ao, Rv[(fj * 16 + r15) * 8 + sg], racc[fj], 0, 0, 0);
#pragma unroll
                for (int fj = 0; fj < 2; ++fj)
#pragma unroll
                    for (int rr = 0; rr < 4; ++rr) {
                        int col = ct0 + q * 4 + rr;
                        int ch  = fj * 16 + r15;
                        float base = rc[col * 36 + ch];
                        rn[col * 36 + ch] = (c0 + col - H >= 0) ? base + racc[fj][rr] : base;
                    }
            }
        }
    }

    if (!LASTHALF) {
        __syncthreads();
        int ch = tid >> 4, t4 = (tid & 15) * 4;
#pragma unroll
        for (int j = 0; j < 4; ++j) {
            int t = r + S * (c0 + t4 + j);
            res_out[((size_t)(b * 32) + ch) * Lc + t] = resB[(H + t4 + j) * 36 + ch];
        }
    }
}

// ============================================================
// G1: bf16 MFMA GEMM, 128t x 64m tile, 48KB dbuf (unchanged R18)
// ============================================================
template <bool RELU_OUT, int NKT>
__global__ __launch_bounds__(256) void gemm_mfma64(
    const __hip_bfloat16* __restrict__ X,
    const __hip_bfloat16* __restrict__ W,
    const float* __restrict__ bias,
    __hip_bfloat16* __restrict__ Y,
    int M, int MB)   // MB = M/64
{
    constexpr int K = NKT * 64;
    __shared__ __align__(16) char smem[49152];
    i32x4* Xs0 = (i32x4*)smem;
    i32x4* Ws0 = (i32x4*)(smem + 16384);
    i32x4* Xs1 = (i32x4*)(smem + 24576);
    i32x4* Ws1 = (i32x4*)(smem + 40960);

    int nwg  = gridDim.x;
    int orig = blockIdx.x;
    int q8 = nwg >> 3, r8 = nwg & 7;
    int xcd = orig & 7, loc = orig >> 3;
    int wgid = (xcd < r8 ? xcd * (q8 + 1) : r8 * (q8 + 1) + (xcd - r8) * q8) + loc;
    int mi  = wgid % MB;
    int byy = wgid / MB;
    int b   = byy / TTILES;
    int t0  = (byy % TTILES) * 128;
    int m0  = mi * 64;

    int tid = threadIdx.x;
    int lane = tid & 63, wid = tid >> 6;
    int r15 = lane & 15, q = lane >> 4;

    int subrow = lane >> 3;
    int g      = (lane & 7) ^ subrow;
    const __hip_bfloat16* xp[4];
    const __hip_bfloat16* wp[2];
#pragma unroll
    for (int i = 0; i < 4; ++i) {
        int r = wid * 32 + i * 8 + subrow;
        int xrow = t0 + r; if (xrow > TGT - 1) xrow = TGT - 1;
        xp[i] = X + ((size_t)(b * TGT + xrow)) * K + g * 8;
    }
#pragma unroll
    for (int i = 0; i < 2; ++i) {
        int r = wid * 16 + i * 8 + subrow;
        wp[i] = W + ((size_t)(m0 + r)) * K + g * 8;
    }

    f32x4 acc[2][4] = {};

#define STAGE(XB, WB)                                                          \
    {                                                                          \
        _Pragma("unroll")                                                      \
        for (int i = 0; i < 4; ++i) {                                          \
            __builtin_amdgcn_global_load_lds((as1v)(void*)xp[i],               \
                (as3v)(void*)&XB[(wid * 4 + i) * 64], 16, 0, 0);               \
            xp[i] += 64;                                                       \
        }                                                                      \
        _Pragma("unroll")                                                      \
        for (int i = 0; i < 2; ++i) {                                          \
            __builtin_amdgcn_global_load_lds((as1v)(void*)wp[i],               \
                (as3v)(void*)&WB[(wid * 2 + i) * 64], 16, 0, 0);               \
            wp[i] += 64;                                                       \
        }                                                                      \
    }

    auto compute = [&](const i32x4* Xb, const i32x4* Wb) {
        const bf16x8* Xv = (const bf16x8*)Xb;
        const bf16x8* Wv = (const bf16x8*)Wb;
#pragma unroll
        for (int kk = 0; kk < 2; ++kk) {
            int sg = (kk * 4 + q) ^ (r15 & 7);
            bf16x8 af[2], bw[4];
#pragma unroll
            for (int ft = 0; ft < 2; ++ft)
                af[ft] = Xv[(wid * 32 + ft * 16 + r15) * 8 + sg];
#pragma unroll
            for (int fj = 0; fj < 4; ++fj)
                bw[fj] = Wv[(fj * 16 + r15) * 8 + sg];
#pragma unroll
            for (int ft = 0; ft < 2; ++ft)
#pragma unroll
                for (int fj = 0; fj < 4; ++fj)
                    acc[ft][fj] = __builtin_amdgcn_mfma_f32_16x16x32_bf16(
                        af[ft], bw[fj], acc[ft][fj], 0, 0, 0);
        }
    };

    STAGE(Xs0, Ws0);

#pragma unroll
    for (int kt2 = 0; kt2 < NKT; kt2 += 2) {
        STAGE(Xs1, Ws1);
        asm volatile("s_waitcnt vmcnt(6)" ::: "memory");
        __builtin_amdgcn_s_barrier();
        __builtin_amdgcn_sched_barrier(0);
        __builtin_amdgcn_s_setprio(1);
        compute(Xs0, Ws0);
        __builtin_amdgcn_s_setprio(0);
        __builtin_amdgcn_sched_barrier(0);
        __builtin_amdgcn_s_barrier();

        if (kt2 + 2 < NKT) {
            STAGE(Xs0, Ws0);
            asm volatile("s_waitcnt vmcnt(6)" ::: "memory");
        } else {
            asm volatile("s_waitcnt vmcnt(0)" ::: "memory");
        }
        __builtin_amdgcn_s_barrier();
        __builtin_amdgcn_sched_barrier(0);
        __builtin_amdgcn_s_setprio(1);
        compute(Xs1, Ws1);
        __builtin_amdgcn_s_setprio(0);
        __builtin_amdgcn_sched_barrier(0);
        __builtin_amdgcn_s_barrier();
    }
#undef STAGE

    __hip_bfloat16* Eb = (__hip_bfloat16*)smem;   // [128][72] padded
#pragma unroll
    for (int ft = 0; ft < 2; ++ft) {
#pragma unroll
        for (int r = 0; r < 4; ++r) {
            int tl = wid * 32 + ft * 16 + q * 4 + r;
#pragma unroll
            for (int fj = 0; fj < 4; ++fj) {
                int ml = fj * 16 + r15;
                float v = acc[ft][fj][r];
                if (bias) v += bias[m0 + ml];
                if (RELU_OUT) v = fmaxf(v, 0.f);
                Eb[tl * 72 + ml] = __float2bfloat16(v);
            }
        }
    }
    __syncthreads();
    {
        int row = tid >> 1, half = tid & 1;
        int t = t0 + row;
        if (t < TGT) {
            __hip_bfloat16* dst = Y + ((size_t)(b * TGT + t)) * M + m0 + half * 32;
            const __hip_bfloat16* src = Eb + row * 72 + half * 32;
#pragma unroll
            for (int k = 0; k < 4; ++k)
                ((i32x4*)dst)[k] = ((const i32x4*)src)[k];
        }
    }
}

// ============================================================
// FUSED G2+G3 (unchanged from R16)
// ============================================================
__global__ __launch_bounds__(512) void gemm_fused23(
    const __hip_bfloat16* __restrict__ X,    // finalT [B*TGT][1024]
    const __hip_bfloat16* __restrict__ W2,   // [512][1024]
    const float* __restrict__ b1,            // [512]
    const __hip_bfloat16* __restrict__ W3,   // [256][512]
    const float* __restrict__ b2,            // [256]
    float* __restrict__ Y)                   // [B*TGT][256]
{
    __shared__ __align__(16) char smem[153600];
    i32x4* Xs[2] = { (i32x4*)smem, (i32x4*)(smem + 8192) };
    i32x4* Ws[2] = { (i32x4*)(smem + 16384), (i32x4*)(smem + 81920) };
    __hip_bfloat16* Hs = (__hip_bfloat16*)(smem + 16384);
    i32x4* W3s[2] = { (i32x4*)(smem + 88064), (i32x4*)(smem + 120832) };

    int nwg  = gridDim.x;
    int orig = blockIdx.x;
    int q8 = nwg >> 3, r8 = nwg & 7;
    int xcd = orig & 7, loc = orig >> 3;
    int wgid = (xcd < r8 ? xcd * (q8 + 1) : r8 * (q8 + 1) + (xcd - r8) * q8) + loc;
    int b  = wgid / T64;
    int t0 = (wgid % T64) * 64;

    int tid = threadIdx.x;
    int lane = tid & 63, wid = tid >> 6;
    int r15 = lane & 15, q = lane >> 4;
    int subrow = lane >> 3;
    int g      = (lane & 7) ^ subrow;

    int xr = wid * 8 + subrow;
    int xrow = t0 + xr; if (xrow > TGT - 1) xrow = TGT - 1;
    const __hip_bfloat16* xp = X + ((size_t)(b * TGT + xrow)) * SCc + g * 8;
    const __hip_bfloat16* wp[8];
#pragma unroll
    for (int i = 0; i < 8; ++i)
        wp[i] = W2 + ((size_t)((wid * 8 + i) * 8 + subrow)) * SCc + g * 8;

    f32x4 acc[4][4] = {};

#define STAGEA(bi)                                                             \
    {                                                                          \
        __builtin_amdgcn_global_load_lds((as1v)(void*)xp,                      \
            (as3v)(void*)&Xs[bi][wid * 64], 16, 0, 0);                         \
        xp += 64;                                                              \
        _Pragma("unroll")                                                      \
        for (int i = 0; i < 8; ++i) {                                          \
            __builtin_amdgcn_global_load_lds((as1v)(void*)wp[i],               \
                (as3v)(void*)&Ws[bi][(wid * 8 + i) * 64], 16, 0, 0);           \
            wp[i] += 64;                                                       \
        }                                                                      \
    }

    auto computeA = [&](const i32x4* Xb, const i32x4* Wb) {
        const bf16x8* Xv = (const bf16x8*)Xb;
        const bf16x8* Wv = (const bf16x8*)Wb;
#pragma unroll
        for (int kk = 0; kk < 2; ++kk) {
            int sg = (kk * 4 + q) ^ (r15 & 7);
            bf16x8 af[4], bw[4];
#pragma unroll
            for (int ft = 0; ft < 4; ++ft)
                af[ft] = Xv[(ft * 16 + r15) * 8 + sg];
#pragma unroll
            for (int fj = 0; fj < 4; ++fj)
                bw[fj] = Wv[(wid * 64 + fj * 16 + r15) * 8 + sg];
#pragma unroll
            for (int ft = 0; ft < 4; ++ft)
#pragma unroll
                for (int fj = 0; fj < 4; ++fj)
                    acc[ft][fj] = __builtin_amdgcn_mfma_f32_16x16x32_bf16(
                        af[ft], bw[fj], acc[ft][fj], 0, 0, 0);
        }
    };

    STAGEA(0);
#pragma unroll
    for (int kt = 0; kt < 16; ++kt) {
        const int cur = kt & 1;
        if (kt + 1 < 16) {
            STAGEA(cur ^ 1);
            asm volatile("s_waitcnt vmcnt(9)" ::: "memory");
        } else {
            asm volatile("s_waitcnt vmcnt(0)" ::: "memory");
        }
        __builtin_amdgcn_s_barrier();
        __builtin_amdgcn_sched_barrier(0);
        __builtin_amdgcn_s_setprio(1);
        computeA(Xs[cur], Ws[cur]);
        __builtin_amdgcn_s_setprio(0);
        __builtin_amdgcn_sched_barrier(0);
        __builtin_amdgcn_s_barrier();
    }
#undef STAGEA

#pragma unroll
    for (int ft = 0; ft < 4; ++ft) {
#pragma unroll
        for (int r = 0; r < 4; ++r) {
            int tl = ft * 16 + q * 4 + r;
#pragma unroll
            for (int fj = 0; fj < 4; ++fj) {
                int m = wid * 64 + fj * 16 + r15;
                float v = acc[ft][fj][r] + b1[m];
                v = fmaxf(v, 0.f);
                Hs[tl * 520 + m] = __float2bfloat16(v);
            }
        }
    }

    const __hip_bfloat16* w3p[4];
#pragma unroll
    for (int i = 0; i < 4; ++i)
        w3p[i] = W3 + ((size_t)((wid * 4 + i) * 8 + subrow)) * ECc + g * 8;

#define STAGEB(bi)                                                             \
    {                                                                          \
        _Pragma("unroll")                                                      \
        for (int i = 0; i < 4; ++i) {                                          \
            __builtin_amdgcn_global_load_lds((as1v)(void*)w3p[i],              \
                (as3v)(void*)&W3s[bi][(wid * 4 + i) * 64], 16, 0, 0);          \
            w3p[i] += 64;                                                      \
        }                                                                      \
    }

    STAGEB(0);
    __syncthreads();

    f32x4 accB[4][2] = {};

#pragma unroll
    for (int kt = 0; kt < 8; ++kt) {
        const int cur = kt & 1;
        if (kt + 1 < 8) {
            STAGEB(cur ^ 1);
            asm volatile("s_waitcnt vmcnt(4)" ::: "memory");
        } else {
            asm volatile("s_waitcnt vmcnt(0)" ::: "memory");
        }
        __builtin_amdgcn_s_barrier();
        __builtin_amdgcn_sched_barrier(0);
        __builtin_amdgcn_s_setprio(1);
        {
            const bf16x8* Wv = (const bf16x8*)W3s[cur];
#pragma unroll
            for (int kk = 0; kk < 2; ++kk) {
                int gk = kt * 8 + kk * 4 + q;
                int sg = (kk * 4 + q) ^ (r15 & 7);
                bf16x8 af[4], bw[2];
#pragma unroll
                for (int ft = 0; ft < 4; ++ft)
                    af[ft] = *(const bf16x8*)&Hs[(ft * 16 + r15) * 520 + gk * 8];
#pragma unroll
                for (int fj = 0; fj < 2; ++fj)
                    bw[fj] = Wv[(wid * 32 + fj * 16 + r15) * 8 + sg];
#pragma unroll
                for (int ft = 0; ft < 4; ++ft)
#pragma unroll
                    for (int fj = 0; fj < 2; ++fj)
                        accB[ft][fj] = __builtin_amdgcn_mfma_f32_16x16x32_bf16(
                            af[ft], bw[fj], accB[ft][fj], 0, 0, 0);
            }
        }
        __builtin_amdgcn_s_setprio(0);
        __builtin_amdgcn_sched_barrier(0);
        __builtin_amdgcn_s_barrier();
    }
#undef STAGEB

#pragma unroll
    for (int ft = 0; ft < 4; ++ft) {
#pragma unroll
        for (int r = 0; r < 4; ++r) {
            int t = t0 + ft * 16 + q * 4 + r;
            if (t < TGT) {
                size_t rowoff = ((size_t)(b * TGT + t)) * OCc;
#pragma unroll
                for (int fj = 0; fj < 2; ++fj) {
                    int m = wid * 32 + fj * 16 + r15;
                    Y[rowoff + m] = accB[ft][fj][r] + b2[m];
                }
            }
        }
    }
}

// ============================================================
extern "C" void kernel_launch(void* const* d_in, const int* in_sizes, int n_in,
                              void* d_out, int out_size, void* d_ws, size_t ws_size,
                              hipStream_t stream)
{
    const float* inputs   = (const float*)d_in[0];
    const float* cond     = (const float*)d_in[1];
    const float* input_w  = (const float*)d_in[2];
    const float* filter_w = (const float*)d_in[3];
    const float* gate_w   = (const float*)d_in[4];
    const float* res_w    = (const float*)d_in[5];
    const float* split_w  = (const float*)d_in[6];
    const float* gcf_w    = (const float*)d_in[7];
    const float* gcs_w    = (const float*)d_in[8];
    const float* f1_w     = (const float*)d_in[9];
    const float* f1_b     = (const float*)d_in[10];
    const float* f2_w     = (const float*)d_in[11];
    const float* f2_b     = (const float*)d_in[12];
    float* out = (float*)d_out;

    char* wsb = (char*)d_ws;
    const size_t RES_B   = (size_t)Bc * RCc * Lc * 4;
    const size_t OUTS_B  = (size_t)Bc * TGT * KTOT * 2;
    const size_t FIN_B   = (size_t)Bc * TGT * SCc * 2;
    const size_t W1_B    = (size_t)SCc * KTOT * 2;
    const size_t W2_B    = (size_t)ECc * SCc * 2;
    const size_t W3_B    = (size_t)OCc * ECc * 2;
    const size_t WFG_B   = (size_t)NL * 64 * 64 * 2;
    const size_t WR_B    = (size_t)NL * 32 * 64 * 2;

    float* res0              = (float*)wsb;                   size_t off = RES_B;
    float* res1              = (float*)(wsb + off);           off += RES_B;
    __hip_bfloat16* outsT    = (__hip_bfloat16*)(wsb + off);  off += OUTS_B;
    __hip_bfloat16* finalT   = (__hip_bfloat16*)(wsb + off);  off += FIN_B;
    __hip_bfloat16* Wp1      = (__hip_bfloat16*)(wsb + off);  off += W1_B;
    __hip_bfloat16* Wp2      = (__hip_bfloat16*)(wsb + off);  off += W2_B;
    __hip_bfloat16* Wp3      = (__hip_bfloat16*)(wsb + off);  off += W3_B;
    __hip_bfloat16* wfgp     = (__hip_bfloat16*)(wsb + off);  off += WFG_B;
    __hip_bfloat16* wrp      = (__hip_bfloat16*)(wsb + off);  off += WR_B;

    // prep: packs + input conv in one node
    {
        const int NTOT = SCc * KTOT + ECc * SCc + OCc * ECc + NL * 64 * 64;
        const int npack = (NTOT + 255) / 256;
        prep_kernel<<<npack + Bc * 128, 256, 0, stream>>>(
            inputs, input_w, res0,
            split_w, f1_w, f2_w, filter_w, gate_w, res_w,
            Wp1, Wp2, Wp3, wfgp, wrp, npack);
    }

    float* rin = res0;
    float* rout = res1;
    const dim3 sgrid(128, Bc);   // 32 residues x 4 segments

    // half 0
    layer_group5<<<dim3(128, Bc), 512, 0, stream>>>(
        rin, rout, outsT, wfgp, wrp, cond, gcf_w, gcs_w, 0, 0);
    { float* t = rin; rin = rout; rout = t; }
    layer_groupS<false><<<sgrid, 512, 0, stream>>>(
        rin, rout, outsT, wfgp, wrp, cond, gcf_w, gcs_w, 5);
    { float* t = rin; rin = rout; rout = t; }
    // half 1: only tiles t0 >= 960 are live downstream (RF analysis)
    layer_group5<<<dim3(113, Bc), 512, 0, stream>>>(
        rin, rout, outsT, wfgp, wrp, cond, gcf_w, gcs_w, 10, 15);
    { float* t = rin; rin = rout; rout = t; }
    layer_groupS<true><<<sgrid, 512, 0, stream>>>(
        rin, rout, outsT, wfgp, wrp, cond, gcf_w, gcs_w, 15);

    // G1: finalT = relu( outsT(12292x640) @ Wp1^T )   -> bf16 [t][1024]
    gemm_mfma64<true, 10><<<(SCc / 64) * Bc * TTILES, 256, 0, stream>>>(
        outsT, Wp1, nullptr, finalT, SCc, SCc / 64);

    // G2+G3 fused: out = (relu(finalT@Wp2^T + f1_b)) @ Wp3^T + f2_b
    gemm_fused23<<<Bc * T64, 512, 0, stream>>>(
        finalT, Wp2, f1_b, Wp3, f2_b, out);
}